// Round 1
// baseline (4918.179 us; speedup 1.0000x reference)
//
#include <hip/hip_runtime.h>
#include <hip/hip_bf16.h>

#define DD 128   // hidden dim
#define TE 128   // edge/row tile per block iteration

// ---------------------------------------------------------------------------
// node projection: x_proj = relu(x @ W_atom + b_atom); h_atom = x_proj
// Tiled fp32 GEMM: W^T staged (XOR-swizzled) in LDS, 128-row A tile in LDS,
// 512 threads, per-thread 8 rows x 4 cols.
// ---------------------------------------------------------------------------
__global__ __launch_bounds__(512)
void node_proj_kernel(const float* __restrict__ x, const float* __restrict__ W,
                      const float* __restrict__ bias,
                      float* __restrict__ x_proj, float* __restrict__ h_atom, int M)
{
    __shared__ __align__(16) float Wt[DD * DD];
    __shared__ __align__(16) float At[TE * DD];
    __shared__ float bs[DD];

    // stage W^T swizzled: element (k,n) -> 16B-chunk unit = n*32 + ((k>>2) ^ (n>>2))
    for (int idx = (int)threadIdx.x; idx < DD * DD; idx += 512) {
        int k = idx >> 7, n = idx & 127;
        int unit = n * 32 + ((k >> 2) ^ (n >> 2));
        Wt[unit * 4 + (k & 3)] = W[idx];
    }
    if (threadIdx.x < DD) bs[threadIdx.x] = bias[threadIdx.x];

    const int r  = threadIdx.x & 127;   // staging row
    const int cb = threadIdx.x >> 7;    // staging col-block (0..3)
    const int nb = threadIdx.x & 31;    // compute: col group (4 cols)
    const int eg = threadIdx.x >> 5;    // compute: row group (8 rows)
    const int ntiles = (M + TE - 1) / TE;

    for (int tile = blockIdx.x; tile < ntiles; tile += gridDim.x) {
        const int m0 = tile * TE;
        __syncthreads();   // protect At/Wt from previous iteration readers
        {
            const int row = m0 + r;
            const float* px = x + (size_t)row * DD + cb * 32;
            #pragma unroll
            for (int c8 = 0; c8 < 8; ++c8) {
                const int c = cb * 8 + c8;
                float4 v = make_float4(0.f, 0.f, 0.f, 0.f);
                if (row < M) v = *(const float4*)(px + c8 * 4);
                *(float4*)(At + (r * 32 + (c ^ (r & 31))) * 4) = v;
            }
        }
        __syncthreads();

        float acc[8][4];
        #pragma unroll
        for (int j = 0; j < 8; ++j) { acc[j][0] = acc[j][1] = acc[j][2] = acc[j][3] = 0.f; }

        #pragma unroll 2
        for (int k4 = 0; k4 < 32; ++k4) {
            const float4 wv0 = *(const float4*)(Wt + ((nb * 4 + 0) * 32 + (k4 ^ nb)) * 4);
            const float4 wv1 = *(const float4*)(Wt + ((nb * 4 + 1) * 32 + (k4 ^ nb)) * 4);
            const float4 wv2 = *(const float4*)(Wt + ((nb * 4 + 2) * 32 + (k4 ^ nb)) * 4);
            const float4 wv3 = *(const float4*)(Wt + ((nb * 4 + 3) * 32 + (k4 ^ nb)) * 4);
            #pragma unroll
            for (int j = 0; j < 8; ++j) {
                const int el = eg * 8 + j;
                const float4 av = *(const float4*)(At + (el * 32 + (k4 ^ (el & 31))) * 4);
                acc[j][0] = fmaf(av.x, wv0.x, acc[j][0]);
                acc[j][0] = fmaf(av.y, wv0.y, acc[j][0]);
                acc[j][0] = fmaf(av.z, wv0.z, acc[j][0]);
                acc[j][0] = fmaf(av.w, wv0.w, acc[j][0]);
                acc[j][1] = fmaf(av.x, wv1.x, acc[j][1]);
                acc[j][1] = fmaf(av.y, wv1.y, acc[j][1]);
                acc[j][1] = fmaf(av.z, wv1.z, acc[j][1]);
                acc[j][1] = fmaf(av.w, wv1.w, acc[j][1]);
                acc[j][2] = fmaf(av.x, wv2.x, acc[j][2]);
                acc[j][2] = fmaf(av.y, wv2.y, acc[j][2]);
                acc[j][2] = fmaf(av.z, wv2.z, acc[j][2]);
                acc[j][2] = fmaf(av.w, wv2.w, acc[j][2]);
                acc[j][3] = fmaf(av.x, wv3.x, acc[j][3]);
                acc[j][3] = fmaf(av.y, wv3.y, acc[j][3]);
                acc[j][3] = fmaf(av.z, wv3.z, acc[j][3]);
                acc[j][3] = fmaf(av.w, wv3.w, acc[j][3]);
            }
        }

        const float b0 = bs[nb * 4 + 0], b1 = bs[nb * 4 + 1];
        const float b2 = bs[nb * 4 + 2], b3 = bs[nb * 4 + 3];
        #pragma unroll
        for (int j = 0; j < 8; ++j) {
            const int row = m0 + eg * 8 + j;
            if (row < M) {
                float4 v;
                v.x = fmaxf(acc[j][0] + b0, 0.f);
                v.y = fmaxf(acc[j][1] + b1, 0.f);
                v.z = fmaxf(acc[j][2] + b2, 0.f);
                v.w = fmaxf(acc[j][3] + b3, 0.f);
                *(float4*)(x_proj + (size_t)row * DD + nb * 4) = v;
                *(float4*)(h_atom + (size_t)row * DD + nb * 4) = v;
            }
        }
    }
}

// ---------------------------------------------------------------------------
// bond projection + layer-0 aggregation:
//   hb = relu(edge_attr @ W_bond + b_bond)   [E,16]@[16,128]
//   atomic sum/max into per-node buffers; store head rows (e < N)
// ---------------------------------------------------------------------------
__global__ __launch_bounds__(256)
void bond_proj_agg_kernel(const float* __restrict__ edge_attr,
                          const float* __restrict__ Wb, const float* __restrict__ bb,
                          const int* __restrict__ idx_i,
                          float* __restrict__ h_head0,
                          float* __restrict__ sum_agg, int* __restrict__ max_agg,
                          int E, int N)
{
    __shared__ float Ws[16 * DD];
    __shared__ float bs2[DD];
    for (int idx = (int)threadIdx.x; idx < 16 * DD; idx += 256) Ws[idx] = Wb[idx];
    if (threadIdx.x < DD) bs2[threadIdx.x] = bb[threadIdx.x];
    __syncthreads();

    const int o  = threadIdx.x & 127;
    const int el = threadIdx.x >> 7;   // 0..1

    for (int ep = blockIdx.x * 2 + el; ep < E; ep += gridDim.x * 2) {
        const float4* ea = (const float4*)(edge_attr + (size_t)ep * 16);
        const float4 a0 = ea[0], a1 = ea[1], a2 = ea[2], a3 = ea[3];
        float acc = bs2[o];
        acc = fmaf(a0.x, Ws[ 0 * DD + o], acc);
        acc = fmaf(a0.y, Ws[ 1 * DD + o], acc);
        acc = fmaf(a0.z, Ws[ 2 * DD + o], acc);
        acc = fmaf(a0.w, Ws[ 3 * DD + o], acc);
        acc = fmaf(a1.x, Ws[ 4 * DD + o], acc);
        acc = fmaf(a1.y, Ws[ 5 * DD + o], acc);
        acc = fmaf(a1.z, Ws[ 6 * DD + o], acc);
        acc = fmaf(a1.w, Ws[ 7 * DD + o], acc);
        acc = fmaf(a2.x, Ws[ 8 * DD + o], acc);
        acc = fmaf(a2.y, Ws[ 9 * DD + o], acc);
        acc = fmaf(a2.z, Ws[10 * DD + o], acc);
        acc = fmaf(a2.w, Ws[11 * DD + o], acc);
        acc = fmaf(a3.x, Ws[12 * DD + o], acc);
        acc = fmaf(a3.y, Ws[13 * DD + o], acc);
        acc = fmaf(a3.z, Ws[14 * DD + o], acc);
        acc = fmaf(a3.w, Ws[15 * DD + o], acc);
        const float v = fmaxf(acc, 0.f);
        const int gi = idx_i[ep];
        atomicAdd(&sum_agg[(size_t)gi * DD + o], v);
        atomicMax(&max_agg[(size_t)gi * DD + o], __float_as_int(v));  // v >= 0: int-bits monotone
        if (ep < N) h_head0[(size_t)ep * DD + o] = v;
    }
}

// ---------------------------------------------------------------------------
// node update: h_atom *= sum_agg * max_agg   (elementwise, float4)
// ---------------------------------------------------------------------------
__global__ __launch_bounds__(256)
void node_update_kernel(float* __restrict__ h_atom, const float* __restrict__ sum_agg,
                        const int* __restrict__ max_agg, int total4)
{
    const int i = blockIdx.x * 256 + threadIdx.x;
    if (i < total4) {
        float4 h = ((const float4*)h_atom)[i];
        const float4 s = ((const float4*)sum_agg)[i];
        const int4  m = ((const int4*)max_agg)[i];
        h.x *= s.x * __int_as_float(m.x);
        h.y *= s.y * __int_as_float(m.y);
        h.z *= s.z * __int_as_float(m.z);
        h.w *= s.w * __int_as_float(m.w);
        ((float4*)h_atom)[i] = h;
    }
}

// ---------------------------------------------------------------------------
// edge GEMM + fused aggregation:
//   A[e] = h_atom[idx_i[e]] - h_head_cur[idx_j[e]]   (idx_j < N)
//   hb   = relu(A @ W + b)
//   atomic sum/max agg by idx_i; store head rows (e < N) if store_head
// ---------------------------------------------------------------------------
__global__ __launch_bounds__(512)
void edge_gemm_agg_kernel(const float* __restrict__ h_atom,
                          const float* __restrict__ h_head_cur,
                          float* __restrict__ h_head_next, int store_head,
                          const int* __restrict__ idx_i, const int* __restrict__ idx_j,
                          const float* __restrict__ W, const float* __restrict__ bias,
                          float* __restrict__ sum_agg, int* __restrict__ max_agg,
                          int E, int N)
{
    __shared__ __align__(16) float Wt[DD * DD];
    __shared__ __align__(16) float At[TE * DD];
    __shared__ float bs[DD];
    __shared__ int ii_s[TE];

    for (int idx = (int)threadIdx.x; idx < DD * DD; idx += 512) {
        int k = idx >> 7, n = idx & 127;
        int unit = n * 32 + ((k >> 2) ^ (n >> 2));
        Wt[unit * 4 + (k & 3)] = W[idx];
    }
    if (threadIdx.x < DD) bs[threadIdx.x] = bias[threadIdx.x];

    const int r  = threadIdx.x & 127;
    const int cb = threadIdx.x >> 7;
    const int nb = threadIdx.x & 31;
    const int eg = threadIdx.x >> 5;
    const int ntiles = (E + TE - 1) / TE;

    for (int tile = blockIdx.x; tile < ntiles; tile += gridDim.x) {
        const int e0 = tile * TE;
        __syncthreads();
        {
            const int e = e0 + r;
            int gi = 0, gj = 0;
            if (e < E) { gi = idx_i[e]; gj = idx_j[e]; }
            if (cb == 0) ii_s[r] = gi;
            const float* pa = h_atom     + (size_t)gi * DD + cb * 32;
            const float* pb = h_head_cur + (size_t)gj * DD + cb * 32;
            #pragma unroll
            for (int c8 = 0; c8 < 8; ++c8) {
                const float4 va = *(const float4*)(pa + c8 * 4);
                const float4 vb = *(const float4*)(pb + c8 * 4);
                float4 d;
                d.x = va.x - vb.x; d.y = va.y - vb.y;
                d.z = va.z - vb.z; d.w = va.w - vb.w;
                const int c = cb * 8 + c8;
                *(float4*)(At + (r * 32 + (c ^ (r & 31))) * 4) = d;
            }
        }
        __syncthreads();

        float acc[8][4];
        #pragma unroll
        for (int j = 0; j < 8; ++j) { acc[j][0] = acc[j][1] = acc[j][2] = acc[j][3] = 0.f; }

        #pragma unroll 2
        for (int k4 = 0; k4 < 32; ++k4) {
            const float4 wv0 = *(const float4*)(Wt + ((nb * 4 + 0) * 32 + (k4 ^ nb)) * 4);
            const float4 wv1 = *(const float4*)(Wt + ((nb * 4 + 1) * 32 + (k4 ^ nb)) * 4);
            const float4 wv2 = *(const float4*)(Wt + ((nb * 4 + 2) * 32 + (k4 ^ nb)) * 4);
            const float4 wv3 = *(const float4*)(Wt + ((nb * 4 + 3) * 32 + (k4 ^ nb)) * 4);
            #pragma unroll
            for (int j = 0; j < 8; ++j) {
                const int el = eg * 8 + j;
                const float4 av = *(const float4*)(At + (el * 32 + (k4 ^ (el & 31))) * 4);
                acc[j][0] = fmaf(av.x, wv0.x, acc[j][0]);
                acc[j][0] = fmaf(av.y, wv0.y, acc[j][0]);
                acc[j][0] = fmaf(av.z, wv0.z, acc[j][0]);
                acc[j][0] = fmaf(av.w, wv0.w, acc[j][0]);
                acc[j][1] = fmaf(av.x, wv1.x, acc[j][1]);
                acc[j][1] = fmaf(av.y, wv1.y, acc[j][1]);
                acc[j][1] = fmaf(av.z, wv1.z, acc[j][1]);
                acc[j][1] = fmaf(av.w, wv1.w, acc[j][1]);
                acc[j][2] = fmaf(av.x, wv2.x, acc[j][2]);
                acc[j][2] = fmaf(av.y, wv2.y, acc[j][2]);
                acc[j][2] = fmaf(av.z, wv2.z, acc[j][2]);
                acc[j][2] = fmaf(av.w, wv2.w, acc[j][2]);
                acc[j][3] = fmaf(av.x, wv3.x, acc[j][3]);
                acc[j][3] = fmaf(av.y, wv3.y, acc[j][3]);
                acc[j][3] = fmaf(av.z, wv3.z, acc[j][3]);
                acc[j][3] = fmaf(av.w, wv3.w, acc[j][3]);
            }
        }

        const float b0 = bs[nb * 4 + 0], b1 = bs[nb * 4 + 1];
        const float b2 = bs[nb * 4 + 2], b3 = bs[nb * 4 + 3];
        #pragma unroll
        for (int j = 0; j < 8; ++j) {
            const int el = eg * 8 + j;
            const int e  = e0 + el;
            if (e < E) {
                float4 v;
                v.x = fmaxf(acc[j][0] + b0, 0.f);
                v.y = fmaxf(acc[j][1] + b1, 0.f);
                v.z = fmaxf(acc[j][2] + b2, 0.f);
                v.w = fmaxf(acc[j][3] + b3, 0.f);
                const int gi = ii_s[el];
                float* sp = sum_agg + (size_t)gi * DD + nb * 4;
                atomicAdd(sp + 0, v.x);
                atomicAdd(sp + 1, v.y);
                atomicAdd(sp + 2, v.z);
                atomicAdd(sp + 3, v.w);
                int* mp = max_agg + (size_t)gi * DD + nb * 4;
                atomicMax(mp + 0, __float_as_int(v.x));
                atomicMax(mp + 1, __float_as_int(v.y));
                atomicMax(mp + 2, __float_as_int(v.z));
                atomicMax(mp + 3, __float_as_int(v.w));
                if (store_head && e < N)
                    *(float4*)(h_head_next + (size_t)e * DD + nb * 4) = v;
            }
        }
    }
}

// ---------------------------------------------------------------------------
// final: msg = sum*max; ha = h_atom * (h_atom * msg);
//        out = [ha, x_proj] @ W_lin + b_lin    [N,256]@[256,64]
// ---------------------------------------------------------------------------
__global__ __launch_bounds__(256)
void final_linear_kernel(const float* __restrict__ h_atom, const float* __restrict__ sum_agg,
                         const int* __restrict__ max_agg, const float* __restrict__ x_proj,
                         const float* __restrict__ Wl, const float* __restrict__ bl,
                         float* __restrict__ out, int Nn)
{
    __shared__ float Wls[256 * 64];
    __shared__ float cat_s[4][256];
    for (int idx = (int)threadIdx.x; idx < 256 * 64; idx += 256) Wls[idx] = Wl[idx];

    const int o  = threadIdx.x & 63;
    const int nl = threadIdx.x >> 6;   // 0..3

    for (int n0 = blockIdx.x * 4; n0 < Nn; n0 += gridDim.x * 4) {
        __syncthreads();   // protect cat_s (and Wls on first iter)
        for (int idx = (int)threadIdx.x; idx < 4 * 256; idx += 256) {
            const int node = n0 + (idx >> 8);
            const int k = idx & 255;
            float v = 0.f;
            if (node < Nn) {
                if (k < 128) {
                    const size_t off = (size_t)node * DD + k;
                    const float ha = h_atom[off];
                    const float m = sum_agg[off] * __int_as_float(max_agg[off]);
                    v = ha * (ha * m);
                } else {
                    v = x_proj[(size_t)node * DD + (k - 128)];
                }
            }
            cat_s[idx >> 8][k] = v;
        }
        __syncthreads();

        const int node = n0 + nl;
        float acc = bl[o];
        #pragma unroll 8
        for (int k = 0; k < 256; ++k) acc = fmaf(cat_s[nl][k], Wls[k * 64 + o], acc);
        if (node < Nn) out[(size_t)node * 64 + o] = acc;
    }
}

// ---------------------------------------------------------------------------
extern "C" void kernel_launch(void* const* d_in, const int* in_sizes, int n_in,
                              void* d_out, int out_size, void* d_ws, size_t ws_size,
                              hipStream_t stream)
{
    const float* x         = (const float*)d_in[0];
    const int*   edge_idx  = (const int*)d_in[1];
    const float* edge_attr = (const float*)d_in[2];
    const float* W_atom    = (const float*)d_in[3];
    const float* b_atom    = (const float*)d_in[4];
    const float* W_bond    = (const float*)d_in[5];
    const float* b_bond    = (const float*)d_in[6];
    const float* W_seq     = (const float*)d_in[7];
    const float* b_seq     = (const float*)d_in[8];
    const float* W_lin     = (const float*)d_in[9];
    const float* b_lin     = (const float*)d_in[10];
    float* out = (float*)d_out;

    const int N = in_sizes[0] / DD;   // 30000
    const int E = in_sizes[1] / 2;    // 480000
    const int* idx_i = edge_idx;
    const int* idx_j = edge_idx + E;

    const size_t nd = (size_t)N * DD;
    float* ws      = (float*)d_ws;
    float* x_proj  = ws;
    float* h_atom  = x_proj + nd;
    float* head0   = h_atom + nd;
    float* head1   = head0 + nd;
    float* sum_agg = head1 + nd;
    int*   max_agg = (int*)(sum_agg + nd);

    hipMemsetAsync(sum_agg, 0, nd * 4, stream);
    hipMemsetAsync(max_agg, 0, nd * 4, stream);

    const int ntiles_n = (N + TE - 1) / TE;
    node_proj_kernel<<<ntiles_n, 512, 0, stream>>>(x, W_atom, b_atom, x_proj, h_atom, N);
    bond_proj_agg_kernel<<<2048, 256, 0, stream>>>(edge_attr, W_bond, b_bond, idx_i,
                                                   head0, sum_agg, max_agg, E, N);

    float* cur = head0;
    float* nxt = head1;
    const int upd_blocks = (int)((nd / 4 + 255) / 256);
    for (int l = 0; l < 3; ++l) {
        node_update_kernel<<<upd_blocks, 256, 0, stream>>>(h_atom, sum_agg, max_agg, (int)(nd / 4));
        hipMemsetAsync(sum_agg, 0, nd * 4, stream);
        hipMemsetAsync(max_agg, 0, nd * 4, stream);
        edge_gemm_agg_kernel<<<256, 512, 0, stream>>>(h_atom, cur, nxt, (l < 2) ? 1 : 0,
                                                      idx_i, idx_j,
                                                      W_seq + (size_t)l * DD * DD,
                                                      b_seq + (size_t)l * DD,
                                                      sum_agg, max_agg, E, N);
        float* t = cur; cur = nxt; nxt = t;
    }

    final_linear_kernel<<<512, 256, 0, stream>>>(h_atom, sum_agg, max_agg, x_proj,
                                                 W_lin, b_lin, out, N);
}

// Round 2
// 1491.517 us; speedup vs baseline: 3.2974x; 3.2974x over previous
//
#include <hip/hip_runtime.h>
#include <hip/hip_bf16.h>

#define DD 128   // hidden dim
#define TE 128   // edge/row tile per block iteration
#define SCB 256  // scan block size

// ---------------------------------------------------------------------------
// counting-sort preprocessing: sort edges by idx_i so aggregation runs are
// contiguous. hist -> 3-step exclusive scan -> scatter.
// ---------------------------------------------------------------------------
__global__ __launch_bounds__(256)
void hist_kernel(const int* __restrict__ idx_i, int* __restrict__ cnt, int E)
{
    const int e = blockIdx.x * 256 + threadIdx.x;
    if (e < E) atomicAdd(&cnt[idx_i[e]], 1);
}

__global__ __launch_bounds__(SCB)
void scan1_kernel(const int* __restrict__ cnt, int* __restrict__ exc,
                  int* __restrict__ bsum, int n)
{
    __shared__ int s[SCB];
    const int i = blockIdx.x * SCB + (int)threadIdx.x;
    const int v = (i < n) ? cnt[i] : 0;
    s[threadIdx.x] = v;
    __syncthreads();
    #pragma unroll
    for (int off = 1; off < SCB; off <<= 1) {
        int t = (threadIdx.x >= off) ? s[threadIdx.x - off] : 0;
        __syncthreads();
        s[threadIdx.x] += t;
        __syncthreads();
    }
    if (i < n) exc[i] = s[threadIdx.x] - v;             // exclusive within block
    if (threadIdx.x == SCB - 1) bsum[blockIdx.x] = s[threadIdx.x];
}

__global__ __launch_bounds__(SCB)
void scan2_kernel(int* __restrict__ bsum, int nb)   // nb <= 256
{
    __shared__ int s[SCB];
    const int v = (threadIdx.x < nb) ? bsum[threadIdx.x] : 0;
    s[threadIdx.x] = v;
    __syncthreads();
    #pragma unroll
    for (int off = 1; off < SCB; off <<= 1) {
        int t = (threadIdx.x >= off) ? s[threadIdx.x - off] : 0;
        __syncthreads();
        s[threadIdx.x] += t;
        __syncthreads();
    }
    if (threadIdx.x < nb) bsum[threadIdx.x] = s[threadIdx.x] - v;  // exclusive
}

__global__ __launch_bounds__(SCB)
void scan3_kernel(int* __restrict__ exc, const int* __restrict__ bsum, int n)
{
    const int i = blockIdx.x * SCB + (int)threadIdx.x;
    if (i < n) exc[i] += bsum[i >> 8];   // exc becomes global exclusive scan = cursor
}

__global__ __launch_bounds__(256)
void scatter_kernel(const int* __restrict__ idx_i, const int* __restrict__ idx_j,
                    int* __restrict__ cursor, int* __restrict__ perm,
                    int* __restrict__ si, int* __restrict__ sj, int E)
{
    const int e = blockIdx.x * 256 + threadIdx.x;
    if (e < E) {
        const int n = idx_i[e];
        const int p = atomicAdd(&cursor[n], 1);
        perm[p] = e;
        si[p] = n;
        sj[p] = idx_j[e];
    }
}

// ---------------------------------------------------------------------------
// node projection: x_proj = relu(x @ W_atom + b_atom); h_atom = x_proj
// ---------------------------------------------------------------------------
__global__ __launch_bounds__(512)
void node_proj_kernel(const float* __restrict__ x, const float* __restrict__ W,
                      const float* __restrict__ bias,
                      float* __restrict__ x_proj, float* __restrict__ h_atom, int M)
{
    __shared__ __align__(16) float Wt[DD * DD];
    __shared__ __align__(16) float At[TE * DD];
    __shared__ float bs[DD];

    for (int idx = (int)threadIdx.x; idx < DD * DD; idx += 512) {
        int k = idx >> 7, n = idx & 127;
        int unit = n * 32 + ((k >> 2) ^ (n >> 2));
        Wt[unit * 4 + (k & 3)] = W[idx];
    }
    if (threadIdx.x < DD) bs[threadIdx.x] = bias[threadIdx.x];

    const int r  = threadIdx.x & 127;
    const int cb = threadIdx.x >> 7;
    const int nb = threadIdx.x & 31;
    const int eg = threadIdx.x >> 5;
    const int ntiles = (M + TE - 1) / TE;

    for (int tile = blockIdx.x; tile < ntiles; tile += gridDim.x) {
        const int m0 = tile * TE;
        __syncthreads();
        {
            const int row = m0 + r;
            const float* px = x + (size_t)row * DD + cb * 32;
            #pragma unroll
            for (int c8 = 0; c8 < 8; ++c8) {
                const int c = cb * 8 + c8;
                float4 v = make_float4(0.f, 0.f, 0.f, 0.f);
                if (row < M) v = *(const float4*)(px + c8 * 4);
                *(float4*)(At + (r * 32 + (c ^ (r & 31))) * 4) = v;
            }
        }
        __syncthreads();

        float acc[8][4];
        #pragma unroll
        for (int j = 0; j < 8; ++j) { acc[j][0] = acc[j][1] = acc[j][2] = acc[j][3] = 0.f; }

        #pragma unroll 2
        for (int k4 = 0; k4 < 32; ++k4) {
            const float4 wv0 = *(const float4*)(Wt + ((nb * 4 + 0) * 32 + (k4 ^ nb)) * 4);
            const float4 wv1 = *(const float4*)(Wt + ((nb * 4 + 1) * 32 + (k4 ^ nb)) * 4);
            const float4 wv2 = *(const float4*)(Wt + ((nb * 4 + 2) * 32 + (k4 ^ nb)) * 4);
            const float4 wv3 = *(const float4*)(Wt + ((nb * 4 + 3) * 32 + (k4 ^ nb)) * 4);
            #pragma unroll
            for (int j = 0; j < 8; ++j) {
                const int el = eg * 8 + j;
                const float4 av = *(const float4*)(At + (el * 32 + (k4 ^ (el & 31))) * 4);
                acc[j][0] = fmaf(av.x, wv0.x, acc[j][0]);
                acc[j][0] = fmaf(av.y, wv0.y, acc[j][0]);
                acc[j][0] = fmaf(av.z, wv0.z, acc[j][0]);
                acc[j][0] = fmaf(av.w, wv0.w, acc[j][0]);
                acc[j][1] = fmaf(av.x, wv1.x, acc[j][1]);
                acc[j][1] = fmaf(av.y, wv1.y, acc[j][1]);
                acc[j][1] = fmaf(av.z, wv1.z, acc[j][1]);
                acc[j][1] = fmaf(av.w, wv1.w, acc[j][1]);
                acc[j][2] = fmaf(av.x, wv2.x, acc[j][2]);
                acc[j][2] = fmaf(av.y, wv2.y, acc[j][2]);
                acc[j][2] = fmaf(av.z, wv2.z, acc[j][2]);
                acc[j][2] = fmaf(av.w, wv2.w, acc[j][2]);
                acc[j][3] = fmaf(av.x, wv3.x, acc[j][3]);
                acc[j][3] = fmaf(av.y, wv3.y, acc[j][3]);
                acc[j][3] = fmaf(av.z, wv3.z, acc[j][3]);
                acc[j][3] = fmaf(av.w, wv3.w, acc[j][3]);
            }
        }

        const float b0 = bs[nb * 4 + 0], b1 = bs[nb * 4 + 1];
        const float b2 = bs[nb * 4 + 2], b3 = bs[nb * 4 + 3];
        #pragma unroll
        for (int j = 0; j < 8; ++j) {
            const int row = m0 + eg * 8 + j;
            if (row < M) {
                float4 v;
                v.x = fmaxf(acc[j][0] + b0, 0.f);
                v.y = fmaxf(acc[j][1] + b1, 0.f);
                v.z = fmaxf(acc[j][2] + b2, 0.f);
                v.w = fmaxf(acc[j][3] + b3, 0.f);
                *(float4*)(x_proj + (size_t)row * DD + nb * 4) = v;
                *(float4*)(h_atom + (size_t)row * DD + nb * 4) = v;
            }
        }
    }
}

// ---------------------------------------------------------------------------
// bond projection + layer-0 aggregation over SORTED edges:
//   hb = relu(edge_attr[perm[p]] @ W_bond + b_bond)
//   run-length-reduced atomic sum/max by si[p]; head store by orig id
// ---------------------------------------------------------------------------
__global__ __launch_bounds__(256)
void bond_proj_agg_kernel(const float* __restrict__ edge_attr,
                          const float* __restrict__ Wb, const float* __restrict__ bb,
                          const int* __restrict__ si, const int* __restrict__ perm,
                          float* __restrict__ h_head0,
                          float* __restrict__ sum_agg, int* __restrict__ max_agg,
                          int E, int N)
{
    __shared__ float Ws[16 * DD];
    __shared__ float bs2[DD];
    __shared__ __align__(16) float ea_s[32][16];
    __shared__ int ii2[32], pm2[32];

    for (int idx = (int)threadIdx.x; idx < 16 * DD; idx += 256) Ws[idx] = Wb[idx];
    if (threadIdx.x < DD) bs2[threadIdx.x] = bb[threadIdx.x];

    const int p0 = blockIdx.x * 32;
    {
        const int t = (int)threadIdx.x;
        const int row = t >> 3;
        const int k2 = (t & 7) * 2;
        const int ppc = min(p0 + row, E - 1);
        const int orig = perm[ppc];
        const float2 v2 = *(const float2*)(edge_attr + (size_t)orig * 16 + k2);
        ea_s[row][k2] = v2.x;
        ea_s[row][k2 + 1] = v2.y;
        if (t < 32) {
            const int q = min(p0 + t, E - 1);
            ii2[t] = si[q];
            pm2[t] = perm[q];
        }
    }
    __syncthreads();

    const int o    = threadIdx.x & 127;
    const int half = threadIdx.x >> 7;   // 0..1: edges half*16 .. half*16+15

    float wcol[16];
    #pragma unroll
    for (int k = 0; k < 16; ++k) wcol[k] = Ws[k * DD + o];
    const float bo = bs2[o];

    int curNode = ii2[half * 16];
    float rs = 0.f, rm = 0.f;
    #pragma unroll 4
    for (int j = 0; j < 16; ++j) {
        const int row = half * 16 + j;
        const float4* ear = (const float4*)(&ea_s[row][0]);
        const float4 q0 = ear[0], q1 = ear[1], q2 = ear[2], q3 = ear[3];
        float acc = bo;
        acc = fmaf(q0.x, wcol[ 0], acc);
        acc = fmaf(q0.y, wcol[ 1], acc);
        acc = fmaf(q0.z, wcol[ 2], acc);
        acc = fmaf(q0.w, wcol[ 3], acc);
        acc = fmaf(q1.x, wcol[ 4], acc);
        acc = fmaf(q1.y, wcol[ 5], acc);
        acc = fmaf(q1.z, wcol[ 6], acc);
        acc = fmaf(q1.w, wcol[ 7], acc);
        acc = fmaf(q2.x, wcol[ 8], acc);
        acc = fmaf(q2.y, wcol[ 9], acc);
        acc = fmaf(q2.z, wcol[10], acc);
        acc = fmaf(q2.w, wcol[11], acc);
        acc = fmaf(q3.x, wcol[12], acc);
        acc = fmaf(q3.y, wcol[13], acc);
        acc = fmaf(q3.z, wcol[14], acc);
        acc = fmaf(q3.w, wcol[15], acc);
        float v = fmaxf(acc, 0.f);
        const int pe = p0 + row;
        if (pe < E) {
            const int orig = pm2[row];
            if (orig < N) h_head0[(size_t)orig * DD + o] = v;
        } else {
            v = 0.f;   // padded row: neutral for sum and (non-negative) max
        }
        const int gi = ii2[row];
        if (gi != curNode) {
            atomicAdd(&sum_agg[(size_t)curNode * DD + o], rs);
            atomicMax(&max_agg[(size_t)curNode * DD + o], __float_as_int(rm));
            curNode = gi; rs = v; rm = v;
        } else {
            rs += v; rm = fmaxf(rm, v);
        }
    }
    atomicAdd(&sum_agg[(size_t)curNode * DD + o], rs);
    atomicMax(&max_agg[(size_t)curNode * DD + o], __float_as_int(rm));
}

// ---------------------------------------------------------------------------
// node update: h_atom *= sum_agg * max_agg   (elementwise, float4)
// ---------------------------------------------------------------------------
__global__ __launch_bounds__(256)
void node_update_kernel(float* __restrict__ h_atom, const float* __restrict__ sum_agg,
                        const int* __restrict__ max_agg, int total4)
{
    const int i = blockIdx.x * 256 + threadIdx.x;
    if (i < total4) {
        float4 h = ((const float4*)h_atom)[i];
        const float4 s = ((const float4*)sum_agg)[i];
        const int4  m = ((const int4*)max_agg)[i];
        h.x *= s.x * __int_as_float(m.x);
        h.y *= s.y * __int_as_float(m.y);
        h.z *= s.z * __int_as_float(m.z);
        h.w *= s.w * __int_as_float(m.w);
        ((float4*)h_atom)[i] = h;
    }
}

// ---------------------------------------------------------------------------
// edge GEMM + fused aggregation over SORTED edges:
//   A[p] = h_atom[si[p]] - h_head_cur[sj[p]]
//   hb   = relu(A @ W + b)
//   run-length-reduced atomic sum/max by si[p]; head store by orig id
// ---------------------------------------------------------------------------
__global__ __launch_bounds__(512)
void edge_gemm_agg_kernel(const float* __restrict__ h_atom,
                          const float* __restrict__ h_head_cur,
                          float* __restrict__ h_head_next, int store_head,
                          const int* __restrict__ si, const int* __restrict__ sj,
                          const int* __restrict__ perm,
                          const float* __restrict__ W, const float* __restrict__ bias,
                          float* __restrict__ sum_agg, int* __restrict__ max_agg,
                          int E, int N)
{
    __shared__ __align__(16) float Wt[DD * DD];
    __shared__ __align__(16) float At[TE * DD];
    __shared__ float bs[DD];
    __shared__ int ii_s[TE];
    __shared__ int perm_s[TE];

    for (int idx = (int)threadIdx.x; idx < DD * DD; idx += 512) {
        int k = idx >> 7, n = idx & 127;
        int unit = n * 32 + ((k >> 2) ^ (n >> 2));
        Wt[unit * 4 + (k & 3)] = W[idx];
    }
    if (threadIdx.x < DD) bs[threadIdx.x] = bias[threadIdx.x];

    const int r  = threadIdx.x & 127;
    const int cb = threadIdx.x >> 7;
    const int nb = threadIdx.x & 31;
    const int eg = threadIdx.x >> 5;
    const int ntiles = (E + TE - 1) / TE;

    // contiguous tile chunks per block: preserves sorted-gather L2 locality
    const int per = (ntiles + gridDim.x - 1) / gridDim.x;
    const int t0 = blockIdx.x * per;
    const int t1 = min(t0 + per, ntiles);

    for (int tile = t0; tile < t1; ++tile) {
        const int e0 = tile * TE;
        __syncthreads();
        {
            const int ec = min(e0 + r, E - 1);
            const int gi = si[ec];
            const int gj = sj[ec];
            if (cb == 0) ii_s[r] = gi;
            if (cb == 1) perm_s[r] = perm[ec];
            const float* pa = h_atom     + (size_t)gi * DD + cb * 32;
            const float* pb = h_head_cur + (size_t)gj * DD + cb * 32;
            #pragma unroll
            for (int c8 = 0; c8 < 8; ++c8) {
                const float4 va = *(const float4*)(pa + c8 * 4);
                const float4 vb = *(const float4*)(pb + c8 * 4);
                float4 d;
                d.x = va.x - vb.x; d.y = va.y - vb.y;
                d.z = va.z - vb.z; d.w = va.w - vb.w;
                const int c = cb * 8 + c8;
                *(float4*)(At + (r * 32 + (c ^ (r & 31))) * 4) = d;
            }
        }
        __syncthreads();

        float acc[8][4];
        #pragma unroll
        for (int j = 0; j < 8; ++j) { acc[j][0] = acc[j][1] = acc[j][2] = acc[j][3] = 0.f; }

        #pragma unroll 2
        for (int k4 = 0; k4 < 32; ++k4) {
            const float4 wv0 = *(const float4*)(Wt + ((nb * 4 + 0) * 32 + (k4 ^ nb)) * 4);
            const float4 wv1 = *(const float4*)(Wt + ((nb * 4 + 1) * 32 + (k4 ^ nb)) * 4);
            const float4 wv2 = *(const float4*)(Wt + ((nb * 4 + 2) * 32 + (k4 ^ nb)) * 4);
            const float4 wv3 = *(const float4*)(Wt + ((nb * 4 + 3) * 32 + (k4 ^ nb)) * 4);
            #pragma unroll
            for (int j = 0; j < 8; ++j) {
                const int el = eg * 8 + j;
                const float4 av = *(const float4*)(At + (el * 32 + (k4 ^ (el & 31))) * 4);
                acc[j][0] = fmaf(av.x, wv0.x, acc[j][0]);
                acc[j][0] = fmaf(av.y, wv0.y, acc[j][0]);
                acc[j][0] = fmaf(av.z, wv0.z, acc[j][0]);
                acc[j][0] = fmaf(av.w, wv0.w, acc[j][0]);
                acc[j][1] = fmaf(av.x, wv1.x, acc[j][1]);
                acc[j][1] = fmaf(av.y, wv1.y, acc[j][1]);
                acc[j][1] = fmaf(av.z, wv1.z, acc[j][1]);
                acc[j][1] = fmaf(av.w, wv1.w, acc[j][1]);
                acc[j][2] = fmaf(av.x, wv2.x, acc[j][2]);
                acc[j][2] = fmaf(av.y, wv2.y, acc[j][2]);
                acc[j][2] = fmaf(av.z, wv2.z, acc[j][2]);
                acc[j][2] = fmaf(av.w, wv2.w, acc[j][2]);
                acc[j][3] = fmaf(av.x, wv3.x, acc[j][3]);
                acc[j][3] = fmaf(av.y, wv3.y, acc[j][3]);
                acc[j][3] = fmaf(av.z, wv3.z, acc[j][3]);
                acc[j][3] = fmaf(av.w, wv3.w, acc[j][3]);
            }
        }

        const float b0 = bs[nb * 4 + 0], b1 = bs[nb * 4 + 1];
        const float b2 = bs[nb * 4 + 2], b3 = bs[nb * 4 + 3];

        // run-length-reduced aggregation epilogue (rows are sorted by node id)
        int curNode = ii_s[eg * 8];
        float4 rs = make_float4(0.f, 0.f, 0.f, 0.f);
        float4 rm = make_float4(0.f, 0.f, 0.f, 0.f);
        #pragma unroll
        for (int j = 0; j < 8; ++j) {
            const int el = eg * 8 + j;
            const int e  = e0 + el;
            float4 v;
            v.x = fmaxf(acc[j][0] + b0, 0.f);
            v.y = fmaxf(acc[j][1] + b1, 0.f);
            v.z = fmaxf(acc[j][2] + b2, 0.f);
            v.w = fmaxf(acc[j][3] + b3, 0.f);
            if (e < E) {
                if (store_head) {
                    const int orig = perm_s[el];
                    if (orig < N)
                        *(float4*)(h_head_next + (size_t)orig * DD + nb * 4) = v;
                }
            } else {
                v = make_float4(0.f, 0.f, 0.f, 0.f);  // neutral padding
            }
            const int gi = ii_s[el];
            if (gi != curNode) {
                float* sp = sum_agg + (size_t)curNode * DD + nb * 4;
                atomicAdd(sp + 0, rs.x);
                atomicAdd(sp + 1, rs.y);
                atomicAdd(sp + 2, rs.z);
                atomicAdd(sp + 3, rs.w);
                int* mp = max_agg + (size_t)curNode * DD + nb * 4;
                atomicMax(mp + 0, __float_as_int(rm.x));
                atomicMax(mp + 1, __float_as_int(rm.y));
                atomicMax(mp + 2, __float_as_int(rm.z));
                atomicMax(mp + 3, __float_as_int(rm.w));
                curNode = gi;
                rs = v; rm = v;
            } else {
                rs.x += v.x; rs.y += v.y; rs.z += v.z; rs.w += v.w;
                rm.x = fmaxf(rm.x, v.x); rm.y = fmaxf(rm.y, v.y);
                rm.z = fmaxf(rm.z, v.z); rm.w = fmaxf(rm.w, v.w);
            }
        }
        {
            float* sp = sum_agg + (size_t)curNode * DD + nb * 4;
            atomicAdd(sp + 0, rs.x);
            atomicAdd(sp + 1, rs.y);
            atomicAdd(sp + 2, rs.z);
            atomicAdd(sp + 3, rs.w);
            int* mp = max_agg + (size_t)curNode * DD + nb * 4;
            atomicMax(mp + 0, __float_as_int(rm.x));
            atomicMax(mp + 1, __float_as_int(rm.y));
            atomicMax(mp + 2, __float_as_int(rm.z));
            atomicMax(mp + 3, __float_as_int(rm.w));
        }
    }
}

// ---------------------------------------------------------------------------
// final: msg = sum*max; ha = h_atom * (h_atom * msg);
//        out = [ha, x_proj] @ W_lin + b_lin    [N,256]@[256,64]
// ---------------------------------------------------------------------------
__global__ __launch_bounds__(256)
void final_linear_kernel(const float* __restrict__ h_atom, const float* __restrict__ sum_agg,
                         const int* __restrict__ max_agg, const float* __restrict__ x_proj,
                         const float* __restrict__ Wl, const float* __restrict__ bl,
                         float* __restrict__ out, int Nn)
{
    __shared__ float Wls[256 * 64];
    __shared__ float cat_s[4][256];
    for (int idx = (int)threadIdx.x; idx < 256 * 64; idx += 256) Wls[idx] = Wl[idx];

    const int o  = threadIdx.x & 63;
    const int nl = threadIdx.x >> 6;   // 0..3

    for (int n0 = blockIdx.x * 4; n0 < Nn; n0 += gridDim.x * 4) {
        __syncthreads();
        for (int idx = (int)threadIdx.x; idx < 4 * 256; idx += 256) {
            const int node = n0 + (idx >> 8);
            const int k = idx & 255;
            float v = 0.f;
            if (node < Nn) {
                if (k < 128) {
                    const size_t off = (size_t)node * DD + k;
                    const float ha = h_atom[off];
                    const float m = sum_agg[off] * __int_as_float(max_agg[off]);
                    v = ha * (ha * m);
                } else {
                    v = x_proj[(size_t)node * DD + (k - 128)];
                }
            }
            cat_s[idx >> 8][k] = v;
        }
        __syncthreads();

        const int node = n0 + nl;
        float acc = bl[o];
        #pragma unroll 8
        for (int k = 0; k < 256; ++k) acc = fmaf(cat_s[nl][k], Wls[k * 64 + o], acc);
        if (node < Nn) out[(size_t)node * 64 + o] = acc;
    }
}

// ---------------------------------------------------------------------------
extern "C" void kernel_launch(void* const* d_in, const int* in_sizes, int n_in,
                              void* d_out, int out_size, void* d_ws, size_t ws_size,
                              hipStream_t stream)
{
    const float* x         = (const float*)d_in[0];
    const int*   edge_idx  = (const int*)d_in[1];
    const float* edge_attr = (const float*)d_in[2];
    const float* W_atom    = (const float*)d_in[3];
    const float* b_atom    = (const float*)d_in[4];
    const float* W_bond    = (const float*)d_in[5];
    const float* b_bond    = (const float*)d_in[6];
    const float* W_seq     = (const float*)d_in[7];
    const float* b_seq     = (const float*)d_in[8];
    const float* W_lin     = (const float*)d_in[9];
    const float* b_lin     = (const float*)d_in[10];
    float* out = (float*)d_out;

    const int N = in_sizes[0] / DD;   // 30000
    const int E = in_sizes[1] / 2;    // 480000
    const int* idx_i = edge_idx;
    const int* idx_j = edge_idx + E;

    const size_t nd = (size_t)N * DD;
    float* ws      = (float*)d_ws;
    float* x_proj  = ws;
    float* h_atom  = x_proj + nd;
    float* head0   = h_atom + nd;
    float* head1   = head0 + nd;
    float* sum_agg = head1 + nd;
    int*   max_agg = (int*)(sum_agg + nd);
    int*   cnt     = max_agg + nd;
    int*   cursor  = cnt + N;
    int*   bsum    = cursor + N;
    int*   perm    = bsum + 256;
    int*   si      = perm + E;
    int*   sj      = si + E;

    // ---- counting sort of edges by idx_i (reused by all 4 aggregations) ----
    hipMemsetAsync(cnt, 0, (size_t)N * 4, stream);
    hist_kernel<<<(E + 255) / 256, 256, 0, stream>>>(idx_i, cnt, E);
    const int nb_scan = (N + SCB - 1) / SCB;
    scan1_kernel<<<nb_scan, SCB, 0, stream>>>(cnt, cursor, bsum, N);
    scan2_kernel<<<1, SCB, 0, stream>>>(bsum, nb_scan);
    scan3_kernel<<<nb_scan, SCB, 0, stream>>>(cursor, bsum, N);
    scatter_kernel<<<(E + 255) / 256, 256, 0, stream>>>(idx_i, idx_j, cursor, perm, si, sj, E);

    hipMemsetAsync(sum_agg, 0, nd * 4, stream);
    hipMemsetAsync(max_agg, 0, nd * 4, stream);

    const int ntiles_n = (N + TE - 1) / TE;
    node_proj_kernel<<<ntiles_n, 512, 0, stream>>>(x, W_atom, b_atom, x_proj, h_atom, N);
    bond_proj_agg_kernel<<<(E + 31) / 32, 256, 0, stream>>>(edge_attr, W_bond, b_bond,
                                                            si, perm, head0,
                                                            sum_agg, max_agg, E, N);

    float* cur = head0;
    float* nxt = head1;
    const int upd_blocks = (int)((nd / 4 + 255) / 256);
    for (int l = 0; l < 3; ++l) {
        node_update_kernel<<<upd_blocks, 256, 0, stream>>>(h_atom, sum_agg, max_agg, (int)(nd / 4));
        hipMemsetAsync(sum_agg, 0, nd * 4, stream);
        hipMemsetAsync(max_agg, 0, nd * 4, stream);
        edge_gemm_agg_kernel<<<256, 512, 0, stream>>>(h_atom, cur, nxt, (l < 2) ? 1 : 0,
                                                      si, sj, perm,
                                                      W_seq + (size_t)l * DD * DD,
                                                      b_seq + (size_t)l * DD,
                                                      sum_agg, max_agg, E, N);
        float* t = cur; cur = nxt; nxt = t;
    }

    final_linear_kernel<<<512, 256, 0, stream>>>(h_atom, sum_agg, max_agg, x_proj,
                                                 W_lin, b_lin, out, N);
}

// Round 3
// 1153.288 us; speedup vs baseline: 4.2645x; 1.2933x over previous
//
#include <hip/hip_runtime.h>
#include <hip/hip_bf16.h>

#define DD 128   // hidden dim
#define TE 128   // edge rows per tile
#define SCB 256  // scan block size

typedef __attribute__((ext_vector_type(8))) short bf16x8;
typedef __attribute__((ext_vector_type(4))) float f32x4;

__device__ __forceinline__ unsigned bf16_rne(float f) {
    unsigned u = __float_as_uint(f);
    return (u + 0x7fffu + ((u >> 16) & 1u)) >> 16;
}

// ---------------------------------------------------------------------------
// counting-sort preprocessing (sort edges by idx_i)
// ---------------------------------------------------------------------------
__global__ __launch_bounds__(256)
void hist_kernel(const int* __restrict__ idx_i, int* __restrict__ cnt, int E)
{
    const int e = blockIdx.x * 256 + threadIdx.x;
    if (e < E) atomicAdd(&cnt[idx_i[e]], 1);
}

__global__ __launch_bounds__(SCB)
void scan1_kernel(const int* __restrict__ cnt, int* __restrict__ exc,
                  int* __restrict__ bsum, int n)
{
    __shared__ int s[SCB];
    const int i = blockIdx.x * SCB + (int)threadIdx.x;
    const int v = (i < n) ? cnt[i] : 0;
    s[threadIdx.x] = v;
    __syncthreads();
    #pragma unroll
    for (int off = 1; off < SCB; off <<= 1) {
        int t = (threadIdx.x >= off) ? s[threadIdx.x - off] : 0;
        __syncthreads();
        s[threadIdx.x] += t;
        __syncthreads();
    }
    if (i < n) exc[i] = s[threadIdx.x] - v;
    if (threadIdx.x == SCB - 1) bsum[blockIdx.x] = s[threadIdx.x];
}

__global__ __launch_bounds__(SCB)
void scan2_kernel(int* __restrict__ bsum, int nb)
{
    __shared__ int s[SCB];
    const int v = (threadIdx.x < nb) ? bsum[threadIdx.x] : 0;
    s[threadIdx.x] = v;
    __syncthreads();
    #pragma unroll
    for (int off = 1; off < SCB; off <<= 1) {
        int t = (threadIdx.x >= off) ? s[threadIdx.x - off] : 0;
        __syncthreads();
        s[threadIdx.x] += t;
        __syncthreads();
    }
    if (threadIdx.x < nb) bsum[threadIdx.x] = s[threadIdx.x] - v;
}

__global__ __launch_bounds__(SCB)
void scan3_kernel(int* __restrict__ exc, const int* __restrict__ bsum, int n)
{
    const int i = blockIdx.x * SCB + (int)threadIdx.x;
    if (i < n) exc[i] += bsum[i >> 8];
}

__global__ __launch_bounds__(256)
void scatter_kernel(const int* __restrict__ idx_i, const int* __restrict__ idx_j,
                    int* __restrict__ cursor, int* __restrict__ perm,
                    int* __restrict__ si, int* __restrict__ sj, int E)
{
    const int e = blockIdx.x * 256 + threadIdx.x;
    if (e < E) {
        const int n = idx_i[e];
        const int p = atomicAdd(&cursor[n], 1);
        perm[p] = e;
        si[p] = n;
        sj[p] = idx_j[e];
    }
}

// ---------------------------------------------------------------------------
// node projection: x_proj = relu(x @ W_atom + b_atom); h_atom = x_proj
// (fp32 VALU path; only ~6% of the edge-GEMM work)
// ---------------------------------------------------------------------------
__global__ __launch_bounds__(512)
void node_proj_kernel(const float* __restrict__ x, const float* __restrict__ W,
                      const float* __restrict__ bias,
                      float* __restrict__ x_proj, float* __restrict__ h_atom, int M)
{
    __shared__ __align__(16) float Wt[DD * DD];
    __shared__ __align__(16) float At[TE * DD];
    __shared__ float bs[DD];

    for (int idx = (int)threadIdx.x; idx < DD * DD; idx += 512) {
        int k = idx >> 7, n = idx & 127;
        int unit = n * 32 + ((k >> 2) ^ (n >> 2));
        Wt[unit * 4 + (k & 3)] = W[idx];
    }
    if (threadIdx.x < DD) bs[threadIdx.x] = bias[threadIdx.x];

    const int r  = threadIdx.x & 127;
    const int cb = threadIdx.x >> 7;
    const int nb = threadIdx.x & 31;
    const int eg = threadIdx.x >> 5;
    const int ntiles = (M + TE - 1) / TE;

    for (int tile = blockIdx.x; tile < ntiles; tile += gridDim.x) {
        const int m0 = tile * TE;
        __syncthreads();
        {
            const int row = m0 + r;
            const float* px = x + (size_t)row * DD + cb * 32;
            #pragma unroll
            for (int c8 = 0; c8 < 8; ++c8) {
                const int c = cb * 8 + c8;
                float4 v = make_float4(0.f, 0.f, 0.f, 0.f);
                if (row < M) v = *(const float4*)(px + c8 * 4);
                *(float4*)(At + (r * 32 + (c ^ (r & 31))) * 4) = v;
            }
        }
        __syncthreads();

        float acc[8][4];
        #pragma unroll
        for (int j = 0; j < 8; ++j) { acc[j][0] = acc[j][1] = acc[j][2] = acc[j][3] = 0.f; }

        #pragma unroll 2
        for (int k4 = 0; k4 < 32; ++k4) {
            const float4 wv0 = *(const float4*)(Wt + ((nb * 4 + 0) * 32 + (k4 ^ nb)) * 4);
            const float4 wv1 = *(const float4*)(Wt + ((nb * 4 + 1) * 32 + (k4 ^ nb)) * 4);
            const float4 wv2 = *(const float4*)(Wt + ((nb * 4 + 2) * 32 + (k4 ^ nb)) * 4);
            const float4 wv3 = *(const float4*)(Wt + ((nb * 4 + 3) * 32 + (k4 ^ nb)) * 4);
            #pragma unroll
            for (int j = 0; j < 8; ++j) {
                const int el = eg * 8 + j;
                const float4 av = *(const float4*)(At + (el * 32 + (k4 ^ (el & 31))) * 4);
                acc[j][0] = fmaf(av.x, wv0.x, acc[j][0]);
                acc[j][0] = fmaf(av.y, wv0.y, acc[j][0]);
                acc[j][0] = fmaf(av.z, wv0.z, acc[j][0]);
                acc[j][0] = fmaf(av.w, wv0.w, acc[j][0]);
                acc[j][1] = fmaf(av.x, wv1.x, acc[j][1]);
                acc[j][1] = fmaf(av.y, wv1.y, acc[j][1]);
                acc[j][1] = fmaf(av.z, wv1.z, acc[j][1]);
                acc[j][1] = fmaf(av.w, wv1.w, acc[j][1]);
                acc[j][2] = fmaf(av.x, wv2.x, acc[j][2]);
                acc[j][2] = fmaf(av.y, wv2.y, acc[j][2]);
                acc[j][2] = fmaf(av.z, wv2.z, acc[j][2]);
                acc[j][2] = fmaf(av.w, wv2.w, acc[j][2]);
                acc[j][3] = fmaf(av.x, wv3.x, acc[j][3]);
                acc[j][3] = fmaf(av.y, wv3.y, acc[j][3]);
                acc[j][3] = fmaf(av.z, wv3.z, acc[j][3]);
                acc[j][3] = fmaf(av.w, wv3.w, acc[j][3]);
            }
        }

        const float b0 = bs[nb * 4 + 0], b1 = bs[nb * 4 + 1];
        const float b2 = bs[nb * 4 + 2], b3 = bs[nb * 4 + 3];
        #pragma unroll
        for (int j = 0; j < 8; ++j) {
            const int row = m0 + eg * 8 + j;
            if (row < M) {
                float4 v;
                v.x = fmaxf(acc[j][0] + b0, 0.f);
                v.y = fmaxf(acc[j][1] + b1, 0.f);
                v.z = fmaxf(acc[j][2] + b2, 0.f);
                v.w = fmaxf(acc[j][3] + b3, 0.f);
                *(float4*)(x_proj + (size_t)row * DD + nb * 4) = v;
                *(float4*)(h_atom + (size_t)row * DD + nb * 4) = v;
            }
        }
    }
}

// ---------------------------------------------------------------------------
// bond projection + layer-0 aggregation over SORTED edges (unchanged)
// ---------------------------------------------------------------------------
__global__ __launch_bounds__(256)
void bond_proj_agg_kernel(const float* __restrict__ edge_attr,
                          const float* __restrict__ Wb, const float* __restrict__ bb,
                          const int* __restrict__ si, const int* __restrict__ perm,
                          float* __restrict__ h_head0,
                          float* __restrict__ sum_agg, int* __restrict__ max_agg,
                          int E, int N)
{
    __shared__ float Ws[16 * DD];
    __shared__ float bs2[DD];
    __shared__ __align__(16) float ea_s[32][16];
    __shared__ int ii2[32], pm2[32];

    for (int idx = (int)threadIdx.x; idx < 16 * DD; idx += 256) Ws[idx] = Wb[idx];
    if (threadIdx.x < DD) bs2[threadIdx.x] = bb[threadIdx.x];

    const int p0 = blockIdx.x * 32;
    {
        const int t = (int)threadIdx.x;
        const int row = t >> 3;
        const int k2 = (t & 7) * 2;
        const int ppc = min(p0 + row, E - 1);
        const int orig = perm[ppc];
        const float2 v2 = *(const float2*)(edge_attr + (size_t)orig * 16 + k2);
        ea_s[row][k2] = v2.x;
        ea_s[row][k2 + 1] = v2.y;
        if (t < 32) {
            const int q = min(p0 + t, E - 1);
            ii2[t] = si[q];
            pm2[t] = perm[q];
        }
    }
    __syncthreads();

    const int o    = threadIdx.x & 127;
    const int half = threadIdx.x >> 7;

    float wcol[16];
    #pragma unroll
    for (int k = 0; k < 16; ++k) wcol[k] = Ws[k * DD + o];
    const float bo = bs2[o];

    int curNode = ii2[half * 16];
    float rs = 0.f, rm = 0.f;
    #pragma unroll 4
    for (int j = 0; j < 16; ++j) {
        const int row = half * 16 + j;
        const float4* ear = (const float4*)(&ea_s[row][0]);
        const float4 q0 = ear[0], q1 = ear[1], q2 = ear[2], q3 = ear[3];
        float acc = bo;
        acc = fmaf(q0.x, wcol[ 0], acc);
        acc = fmaf(q0.y, wcol[ 1], acc);
        acc = fmaf(q0.z, wcol[ 2], acc);
        acc = fmaf(q0.w, wcol[ 3], acc);
        acc = fmaf(q1.x, wcol[ 4], acc);
        acc = fmaf(q1.y, wcol[ 5], acc);
        acc = fmaf(q1.z, wcol[ 6], acc);
        acc = fmaf(q1.w, wcol[ 7], acc);
        acc = fmaf(q2.x, wcol[ 8], acc);
        acc = fmaf(q2.y, wcol[ 9], acc);
        acc = fmaf(q2.z, wcol[10], acc);
        acc = fmaf(q2.w, wcol[11], acc);
        acc = fmaf(q3.x, wcol[12], acc);
        acc = fmaf(q3.y, wcol[13], acc);
        acc = fmaf(q3.z, wcol[14], acc);
        acc = fmaf(q3.w, wcol[15], acc);
        float v = fmaxf(acc, 0.f);
        const int pe = p0 + row;
        if (pe < E) {
            const int orig = pm2[row];
            if (orig < N) h_head0[(size_t)orig * DD + o] = v;
        } else {
            v = 0.f;
        }
        const int gi = ii2[row];
        if (gi != curNode) {
            atomicAdd(&sum_agg[(size_t)curNode * DD + o], rs);
            atomicMax(&max_agg[(size_t)curNode * DD + o], __float_as_int(rm));
            curNode = gi; rs = v; rm = v;
        } else {
            rs += v; rm = fmaxf(rm, v);
        }
    }
    atomicAdd(&sum_agg[(size_t)curNode * DD + o], rs);
    atomicMax(&max_agg[(size_t)curNode * DD + o], __float_as_int(rm));
}

// ---------------------------------------------------------------------------
// node update (+ fused re-zero of sum/max for the next layer's atomics)
// ---------------------------------------------------------------------------
__global__ __launch_bounds__(256)
void node_update_kernel(float* __restrict__ h_atom, float* __restrict__ sum_agg,
                        int* __restrict__ max_agg, int total4)
{
    const int i = blockIdx.x * 256 + threadIdx.x;
    if (i < total4) {
        float4 h = ((const float4*)h_atom)[i];
        const float4 s = ((const float4*)sum_agg)[i];
        const int4  m = ((const int4*)max_agg)[i];
        h.x *= s.x * __int_as_float(m.x);
        h.y *= s.y * __int_as_float(m.y);
        h.z *= s.z * __int_as_float(m.z);
        h.w *= s.w * __int_as_float(m.w);
        ((float4*)h_atom)[i] = h;
        ((float4*)sum_agg)[i] = make_float4(0.f, 0.f, 0.f, 0.f);
        ((int4*)max_agg)[i]   = make_int4(0, 0, 0, 0);
    }
}

// ---------------------------------------------------------------------------
// edge GEMM via split-bf16 MFMA + fused sorted aggregation.
//   A[p] = h_atom[si[p]] - h_head_cur[sj[p]]  (f32)  -> hi/lo bf16 in LDS
//   W    -> hi/lo bf16, transposed [col][k], in LDS (once per block)
//   C    = Ahi*Whi + Ahi*Wlo + Alo*Whi  (f32 acc, MFMA 16x16x32)
//   epilogue: relu(+bias), run-length atomics by si, head store by perm
// 1024 threads = 16 waves in a 4x4 grid; each wave owns a 32x32 output tile.
// ---------------------------------------------------------------------------
__global__ __launch_bounds__(1024)
void edge_gemm_mfma_kernel(const float* __restrict__ h_atom,
                           const float* __restrict__ h_head_cur,
                           float* __restrict__ h_head_next, int store_head,
                           const int* __restrict__ si, const int* __restrict__ sj,
                           const int* __restrict__ perm,
                           const float* __restrict__ W, const float* __restrict__ bias,
                           float* __restrict__ sum_agg, int* __restrict__ max_agg,
                           int E, int N, int ntiles)
{
    // LDS layout (bytes):
    // [0,32768)       Whi  bf16 [col][k], XOR-swizzled
    // [32768,65536)   Wlo
    // [65536,98304)   Ahi  bf16 [row][k], XOR-swizzled
    // [98304,131072)  Alo              (A region doubles as f32 W scratch)
    // [131072,131584) bias f32[128]
    // [131584,132096) ii_s int[128]
    // [132096,132608) pm_s int[128]
    __shared__ __align__(16) unsigned char SM[132608];
    char*  const Whi = (char*)SM;
    char*  const Wlo = (char*)SM + 32768;
    char*  const Ahi = (char*)SM + 65536;
    char*  const Alo = (char*)SM + 98304;
    float* const Wf  = (float*)(SM + 65536);
    float* const bs  = (float*)(SM + 131072);
    int*   const ii_s = (int*)(SM + 131584);
    int*   const pm_s = (int*)(SM + 132096);

    const int t = (int)threadIdx.x;

    // ---- prologue phase 1: coalesced W f32 -> LDS scratch ----
    {
        const float4* Wg = (const float4*)W;
        float4* Wd = (float4*)Wf;
        #pragma unroll
        for (int i = 0; i < 4; ++i) Wd[t + i * 1024] = Wg[t + i * 1024];
        if (t < DD) bs[t] = bias[t];
    }
    __syncthreads();
    // ---- prologue phase 2: split + transpose into Whi/Wlo ----
    {
        const int col = t >> 3;
        const int kb  = (t & 7) * 16;
        unsigned h16[16], l16[16];
        #pragma unroll
        for (int j = 0; j < 16; ++j) {
            const float w = Wf[(size_t)(kb + j) * DD + col];
            const unsigned hb = bf16_rne(w);
            const float hf = __uint_as_float(hb << 16);
            h16[j] = hb;
            l16[j] = bf16_rne(w - hf);
        }
        #pragma unroll
        for (int c = 0; c < 2; ++c) {
            uint4 ph, pl;
            ph.x = h16[c*8+0] | (h16[c*8+1] << 16);
            ph.y = h16[c*8+2] | (h16[c*8+3] << 16);
            ph.z = h16[c*8+4] | (h16[c*8+5] << 16);
            ph.w = h16[c*8+6] | (h16[c*8+7] << 16);
            pl.x = l16[c*8+0] | (l16[c*8+1] << 16);
            pl.y = l16[c*8+2] | (l16[c*8+3] << 16);
            pl.z = l16[c*8+4] | (l16[c*8+5] << 16);
            pl.w = l16[c*8+6] | (l16[c*8+7] << 16);
            const int off = ((col * 256 + (kb + c * 8) * 2)) ^ ((col & 7) << 4);
            *(uint4*)(Whi + off) = ph;
            *(uint4*)(Wlo + off) = pl;
        }
    }

    // wave/lane decomposition
    const int w  = t >> 6;
    const int l  = t & 63;
    const int wm = w >> 2;     // 0..3 : row block (32 rows)
    const int wn = w & 3;      // 0..3 : col block (32 cols)
    const int g  = l >> 4;     // 0..3 : k-group / D row-group
    const int q  = l & 15;     // 0..15: A row / B col / D col

    const int per = (ntiles + (int)gridDim.x - 1) / (int)gridDim.x;
    const int t0 = blockIdx.x * per;
    const int t1 = min(t0 + per, ntiles);

    for (int tile = t0; tile < t1; ++tile) {
        const int e0 = tile * TE;
        __syncthreads();   // previous tile's MFMA/epilogue done; A region free

        // ---- stage A tile: gather, subtract, split, swizzled LDS write ----
        if (t < TE) {
            const int ec = min(e0 + t, E - 1);
            ii_s[t] = si[ec];
            pm_s[t] = perm[ec];
        }
        #pragma unroll
        for (int i = 0; i < 2; ++i) {
            const int task = t + i * 1024;
            const int row  = task >> 4;
            const int c    = task & 15;       // 8-element k-chunk
            const int ec = min(e0 + row, E - 1);
            const int gi = si[ec];
            const int gj = sj[ec];
            const float* pa = h_atom     + (size_t)gi * DD + c * 8;
            const float* pb = h_head_cur + (size_t)gj * DD + c * 8;
            const float4 a0 = *(const float4*)pa;
            const float4 a1 = *(const float4*)(pa + 4);
            const float4 b0 = *(const float4*)pb;
            const float4 b1 = *(const float4*)(pb + 4);
            float d[8];
            d[0] = a0.x - b0.x; d[1] = a0.y - b0.y; d[2] = a0.z - b0.z; d[3] = a0.w - b0.w;
            d[4] = a1.x - b1.x; d[5] = a1.y - b1.y; d[6] = a1.z - b1.z; d[7] = a1.w - b1.w;
            unsigned h8[8], l8[8];
            #pragma unroll
            for (int j = 0; j < 8; ++j) {
                const unsigned hb = bf16_rne(d[j]);
                const float hf = __uint_as_float(hb << 16);
                h8[j] = hb;
                l8[j] = bf16_rne(d[j] - hf);
            }
            uint4 ph, pl;
            ph.x = h8[0] | (h8[1] << 16);
            ph.y = h8[2] | (h8[3] << 16);
            ph.z = h8[4] | (h8[5] << 16);
            ph.w = h8[6] | (h8[7] << 16);
            pl.x = l8[0] | (l8[1] << 16);
            pl.y = l8[2] | (l8[3] << 16);
            pl.z = l8[4] | (l8[5] << 16);
            pl.w = l8[6] | (l8[7] << 16);
            const int off = ((row * 256 + c * 16)) ^ ((row & 7) << 4);
            *(uint4*)(Ahi + off) = ph;
            *(uint4*)(Alo + off) = pl;
        }
        __syncthreads();

        // ---- MFMA: C = Ahi*Whi + Ahi*Wlo + Alo*Whi ----
        f32x4 acc[2][2];
        const f32x4 zero = {0.f, 0.f, 0.f, 0.f};
        acc[0][0] = zero; acc[0][1] = zero; acc[1][0] = zero; acc[1][1] = zero;

        #pragma unroll
        for (int ks = 0; ks < 4; ++ks) {
            const int kbyte = ks * 64 + g * 16;
            bf16x8 ah[2], al[2], bh[2], bl[2];
            #pragma unroll
            for (int m = 0; m < 2; ++m) {
                const int row = wm * 32 + m * 16 + q;
                const int off = (row * 256 + kbyte) ^ ((row & 7) << 4);
                ah[m] = *(const bf16x8*)(Ahi + off);
                al[m] = *(const bf16x8*)(Alo + off);
            }
            #pragma unroll
            for (int n = 0; n < 2; ++n) {
                const int colv = wn * 32 + n * 16 + q;
                const int off = (colv * 256 + kbyte) ^ ((colv & 7) << 4);
                bh[n] = *(const bf16x8*)(Whi + off);
                bl[n] = *(const bf16x8*)(Wlo + off);
            }
            #pragma unroll
            for (int m = 0; m < 2; ++m)
                #pragma unroll
                for (int n = 0; n < 2; ++n)
                    acc[m][n] = __builtin_amdgcn_mfma_f32_16x16x32_bf16(ah[m], bh[n], acc[m][n], 0, 0, 0);
            #pragma unroll
            for (int m = 0; m < 2; ++m)
                #pragma unroll
                for (int n = 0; n < 2; ++n)
                    acc[m][n] = __builtin_amdgcn_mfma_f32_16x16x32_bf16(ah[m], bl[n], acc[m][n], 0, 0, 0);
            #pragma unroll
            for (int m = 0; m < 2; ++m)
                #pragma unroll
                for (int n = 0; n < 2; ++n)
                    acc[m][n] = __builtin_amdgcn_mfma_f32_16x16x32_bf16(al[m], bh[n], acc[m][n], 0, 0, 0);
        }

        // ---- epilogue: relu(+bias), head store, run-length atomics ----
        #pragma unroll
        for (int n = 0; n < 2; ++n) {
            const int colv = wn * 32 + n * 16 + q;
            const float bcol = bs[colv];
            #pragma unroll
            for (int m = 0; m < 2; ++m) {
                const int r0 = wm * 32 + m * 16 + g * 4;
                int node = ii_s[r0];
                float rs = 0.f, rm = 0.f;
                #pragma unroll
                for (int r = 0; r < 4; ++r) {
                    const int row = r0 + r;
                    const int e = e0 + row;
                    float v = fmaxf(acc[m][n][r] + bcol, 0.f);
                    if (e < E) {
                        if (store_head) {
                            const int orig = pm_s[row];
                            if (orig < N)
                                h_head_next[(size_t)orig * DD + colv] = v;
                        }
                    } else {
                        v = 0.f;   // neutral padding
                    }
                    const int nd2 = ii_s[row];
                    if (nd2 != node) {
                        atomicAdd(&sum_agg[(size_t)node * DD + colv], rs);
                        atomicMax(&max_agg[(size_t)node * DD + colv], __float_as_int(rm));
                        node = nd2; rs = v; rm = v;
                    } else {
                        rs += v; rm = fmaxf(rm, v);
                    }
                }
                atomicAdd(&sum_agg[(size_t)node * DD + colv], rs);
                atomicMax(&max_agg[(size_t)node * DD + colv], __float_as_int(rm));
            }
        }
    }
}

// ---------------------------------------------------------------------------
// final: msg = sum*max; ha = h_atom * (h_atom * msg);
//        out = [ha, x_proj] @ W_lin + b_lin
// ---------------------------------------------------------------------------
__global__ __launch_bounds__(256)
void final_linear_kernel(const float* __restrict__ h_atom, const float* __restrict__ sum_agg,
                         const int* __restrict__ max_agg, const float* __restrict__ x_proj,
                         const float* __restrict__ Wl, const float* __restrict__ bl,
                         float* __restrict__ out, int Nn)
{
    __shared__ float Wls[256 * 64];
    __shared__ float cat_s[4][256];
    for (int idx = (int)threadIdx.x; idx < 256 * 64; idx += 256) Wls[idx] = Wl[idx];

    const int o  = threadIdx.x & 63;
    const int nl = threadIdx.x >> 6;

    for (int n0 = blockIdx.x * 4; n0 < Nn; n0 += gridDim.x * 4) {
        __syncthreads();
        for (int idx = (int)threadIdx.x; idx < 4 * 256; idx += 256) {
            const int node = n0 + (idx >> 8);
            const int k = idx & 255;
            float v = 0.f;
            if (node < Nn) {
                if (k < 128) {
                    const size_t off = (size_t)node * DD + k;
                    const float ha = h_atom[off];
                    const float m = sum_agg[off] * __int_as_float(max_agg[off]);
                    v = ha * (ha * m);
                } else {
                    v = x_proj[(size_t)node * DD + (k - 128)];
                }
            }
            cat_s[idx >> 8][k] = v;
        }
        __syncthreads();

        const int node = n0 + nl;
        float acc = bl[o];
        #pragma unroll 8
        for (int k = 0; k < 256; ++k) acc = fmaf(cat_s[nl][k], Wls[k * 64 + o], acc);
        if (node < Nn) out[(size_t)node * 64 + o] = acc;
    }
}

// ---------------------------------------------------------------------------
extern "C" void kernel_launch(void* const* d_in, const int* in_sizes, int n_in,
                              void* d_out, int out_size, void* d_ws, size_t ws_size,
                              hipStream_t stream)
{
    const float* x         = (const float*)d_in[0];
    const int*   edge_idx  = (const int*)d_in[1];
    const float* edge_attr = (const float*)d_in[2];
    const float* W_atom    = (const float*)d_in[3];
    const float* b_atom    = (const float*)d_in[4];
    const float* W_bond    = (const float*)d_in[5];
    const float* b_bond    = (const float*)d_in[6];
    const float* W_seq     = (const float*)d_in[7];
    const float* b_seq     = (const float*)d_in[8];
    const float* W_lin     = (const float*)d_in[9];
    const float* b_lin     = (const float*)d_in[10];
    float* out = (float*)d_out;

    const int N = in_sizes[0] / DD;   // 30000
    const int E = in_sizes[1] / 2;    // 480000
    const int* idx_i = edge_idx;
    const int* idx_j = edge_idx + E;

    const size_t nd = (size_t)N * DD;
    float* ws      = (float*)d_ws;
    float* x_proj  = ws;
    float* h_atom  = x_proj + nd;
    float* head0   = h_atom + nd;
    float* head1   = head0 + nd;
    float* sum_agg = head1 + nd;
    int*   max_agg = (int*)(sum_agg + nd);
    int*   cnt     = max_agg + nd;
    int*   cursor  = cnt + N;
    int*   bsum    = cursor + N;
    int*   perm    = bsum + 256;
    int*   si      = perm + E;
    int*   sj      = si + E;

    // ---- counting sort of edges by idx_i ----
    hipMemsetAsync(cnt, 0, (size_t)N * 4, stream);
    hist_kernel<<<(E + 255) / 256, 256, 0, stream>>>(idx_i, cnt, E);
    const int nb_scan = (N + SCB - 1) / SCB;
    scan1_kernel<<<nb_scan, SCB, 0, stream>>>(cnt, cursor, bsum, N);
    scan2_kernel<<<1, SCB, 0, stream>>>(bsum, nb_scan);
    scan3_kernel<<<nb_scan, SCB, 0, stream>>>(cursor, bsum, N);
    scatter_kernel<<<(E + 255) / 256, 256, 0, stream>>>(idx_i, idx_j, cursor, perm, si, sj, E);

    hipMemsetAsync(sum_agg, 0, nd * 4, stream);
    hipMemsetAsync(max_agg, 0, nd * 4, stream);

    const int ntiles_n = (N + TE - 1) / TE;
    node_proj_kernel<<<ntiles_n, 512, 0, stream>>>(x, W_atom, b_atom, x_proj, h_atom, N);
    bond_proj_agg_kernel<<<(E + 31) / 32, 256, 0, stream>>>(edge_attr, W_bond, b_bond,
                                                            si, perm, head0,
                                                            sum_agg, max_agg, E, N);

    const int ntiles_e = (E + TE - 1) / TE;
    float* cur = head0;
    float* nxt = head1;
    const int upd_blocks = (int)((nd / 4 + 255) / 256);
    for (int l = 0; l < 3; ++l) {
        // node update also re-zeroes sum/max for this layer's aggregation
        node_update_kernel<<<upd_blocks, 256, 0, stream>>>(h_atom, sum_agg, max_agg, (int)(nd / 4));
        edge_gemm_mfma_kernel<<<256, 1024, 0, stream>>>(h_atom, cur, nxt, (l < 2) ? 1 : 0,
                                                        si, sj, perm,
                                                        W_seq + (size_t)l * DD * DD,
                                                        b_seq + (size_t)l * DD,
                                                        sum_agg, max_agg, E, N, ntiles_e);
        float* t = cur; cur = nxt; nxt = t;
    }

    final_linear_kernel<<<512, 256, 0, stream>>>(h_atom, sum_agg, max_agg, x_proj,
                                                 W_lin, b_lin, out, N);
}

// Round 4
// 564.920 us; speedup vs baseline: 8.7060x; 2.0415x over previous
//
#include <hip/hip_runtime.h>
#include <hip/hip_bf16.h>

#define DD 128   // hidden dim
#define SCB 256  // scan block size

typedef __attribute__((ext_vector_type(8))) short bf16x8;
typedef __attribute__((ext_vector_type(4))) float f32x4;

__device__ __forceinline__ unsigned bf16_rne(float f) {
    unsigned u = __float_as_uint(f);
    return (u + 0x7fffu + ((u >> 16) & 1u)) >> 16;
}

// ---------------------------------------------------------------------------
// counting-sort preprocessing (sort edges by idx_i)
// ---------------------------------------------------------------------------
__global__ __launch_bounds__(256)
void hist_kernel(const int* __restrict__ idx_i, int* __restrict__ cnt, int E)
{
    const int e = blockIdx.x * 256 + threadIdx.x;
    if (e < E) atomicAdd(&cnt[idx_i[e]], 1);
}

__global__ __launch_bounds__(SCB)
void scan1_kernel(const int* __restrict__ cnt, int* __restrict__ exc,
                  int* __restrict__ bsum, int n)
{
    __shared__ int s[SCB];
    const int i = blockIdx.x * SCB + (int)threadIdx.x;
    const int v = (i < n) ? cnt[i] : 0;
    s[threadIdx.x] = v;
    __syncthreads();
    #pragma unroll
    for (int off = 1; off < SCB; off <<= 1) {
        int t = (threadIdx.x >= off) ? s[threadIdx.x - off] : 0;
        __syncthreads();
        s[threadIdx.x] += t;
        __syncthreads();
    }
    if (i < n) exc[i] = s[threadIdx.x] - v;
    if (threadIdx.x == SCB - 1) bsum[blockIdx.x] = s[threadIdx.x];
}

__global__ __launch_bounds__(SCB)
void scan2_kernel(int* __restrict__ bsum, int nb)
{
    __shared__ int s[SCB];
    const int v = (threadIdx.x < nb) ? bsum[threadIdx.x] : 0;
    s[threadIdx.x] = v;
    __syncthreads();
    #pragma unroll
    for (int off = 1; off < SCB; off <<= 1) {
        int t = (threadIdx.x >= off) ? s[threadIdx.x - off] : 0;
        __syncthreads();
        s[threadIdx.x] += t;
        __syncthreads();
    }
    if (threadIdx.x < nb) bsum[threadIdx.x] = s[threadIdx.x] - v;
}

__global__ __launch_bounds__(SCB)
void scan3_kernel(int* __restrict__ exc, const int* __restrict__ bsum, int n)
{
    const int i = blockIdx.x * SCB + (int)threadIdx.x;
    if (i < n) exc[i] += bsum[i >> 8];
}

__global__ __launch_bounds__(256)
void scatter_kernel(const int* __restrict__ idx_i, const int* __restrict__ idx_j,
                    int* __restrict__ cursor, int* __restrict__ perm,
                    int* __restrict__ si, int* __restrict__ sj, int E)
{
    const int e = blockIdx.x * 256 + threadIdx.x;
    if (e < E) {
        const int n = idx_i[e];
        const int p = atomicAdd(&cursor[n], 1);
        perm[p] = e;
        si[p] = n;
        sj[p] = idx_j[e];
    }
}

// ---------------------------------------------------------------------------
// generic 128-K split-bf16 MFMA GEMM:
//   rows r < nA read from A0, else from A1 (row r-nA)
//   out = (relu?)(A @ W + (bias?))  -> out0 [, out1]
// 1024 threads = 16 waves (4x4), 128x128 tile, C = Ahi*Whi + Ahi*Wlo + Alo*Whi
// ---------------------------------------------------------------------------
__global__ __launch_bounds__(1024)
void gemm128_mfma_kernel(const float* __restrict__ A0, const float* __restrict__ A1,
                         int nA, int nTotal,
                         const float* __restrict__ W, const float* __restrict__ bias,
                         int do_relu, float* __restrict__ out0, float* __restrict__ out1,
                         int ntiles)
{
    // LDS: Whi 32K | Wlo 32K | Ahi 32K | Alo 32K | bias 512
    // (A region doubles as f32 W scratch during prologue)
    __shared__ __align__(16) unsigned char SM[131584];
    char*  const Whi = (char*)SM;
    char*  const Wlo = (char*)SM + 32768;
    char*  const Ahi = (char*)SM + 65536;
    char*  const Alo = (char*)SM + 98304;
    float* const Wf  = (float*)(SM + 65536);
    float* const bs  = (float*)(SM + 131072);

    const int t = (int)threadIdx.x;

    // ---- prologue phase 1: coalesced W f32 -> LDS scratch ----
    {
        const float4* Wg = (const float4*)W;
        float4* Wd = (float4*)Wf;
        #pragma unroll
        for (int i = 0; i < 4; ++i) Wd[t + i * 1024] = Wg[t + i * 1024];
        if (t < DD) bs[t] = bias ? bias[t] : 0.f;
    }
    __syncthreads();
    // ---- prologue phase 2: split + transpose into Whi/Wlo ----
    {
        const int col = t >> 3;
        const int kb  = (t & 7) * 16;
        unsigned h16[16], l16[16];
        #pragma unroll
        for (int j = 0; j < 16; ++j) {
            const float w = Wf[(size_t)(kb + j) * DD + col];
            const unsigned hb = bf16_rne(w);
            const float hf = __uint_as_float(hb << 16);
            h16[j] = hb;
            l16[j] = bf16_rne(w - hf);
        }
        #pragma unroll
        for (int c = 0; c < 2; ++c) {
            uint4 ph, pl;
            ph.x = h16[c*8+0] | (h16[c*8+1] << 16);
            ph.y = h16[c*8+2] | (h16[c*8+3] << 16);
            ph.z = h16[c*8+4] | (h16[c*8+5] << 16);
            ph.w = h16[c*8+6] | (h16[c*8+7] << 16);
            pl.x = l16[c*8+0] | (l16[c*8+1] << 16);
            pl.y = l16[c*8+2] | (l16[c*8+3] << 16);
            pl.z = l16[c*8+4] | (l16[c*8+5] << 16);
            pl.w = l16[c*8+6] | (l16[c*8+7] << 16);
            const int off = ((col * 256 + (kb + c * 8) * 2)) ^ ((col & 7) << 4);
            *(uint4*)(Whi + off) = ph;
            *(uint4*)(Wlo + off) = pl;
        }
    }

    const int w  = t >> 6;
    const int l  = t & 63;
    const int wm = w >> 2;
    const int wn = w & 3;
    const int g  = l >> 4;
    const int q  = l & 15;

    for (int tile = blockIdx.x; tile < ntiles; tile += gridDim.x) {
        const int e0 = tile * 128;
        __syncthreads();

        // ---- stage A tile: split, swizzled LDS write ----
        #pragma unroll
        for (int i = 0; i < 2; ++i) {
            const int task = t + i * 1024;
            const int row  = task >> 4;
            const int c    = task & 15;
            const int rr = min(e0 + row, nTotal - 1);
            const float* pa = (rr < nA) ? (A0 + (size_t)rr * DD)
                                        : (A1 + (size_t)(rr - nA) * DD);
            const float4 a0 = *(const float4*)(pa + c * 8);
            const float4 a1 = *(const float4*)(pa + c * 8 + 4);
            float d[8] = {a0.x, a0.y, a0.z, a0.w, a1.x, a1.y, a1.z, a1.w};
            unsigned h8[8], l8[8];
            #pragma unroll
            for (int j = 0; j < 8; ++j) {
                const unsigned hb = bf16_rne(d[j]);
                const float hf = __uint_as_float(hb << 16);
                h8[j] = hb;
                l8[j] = bf16_rne(d[j] - hf);
            }
            uint4 ph, pl;
            ph.x = h8[0] | (h8[1] << 16);
            ph.y = h8[2] | (h8[3] << 16);
            ph.z = h8[4] | (h8[5] << 16);
            ph.w = h8[6] | (h8[7] << 16);
            pl.x = l8[0] | (l8[1] << 16);
            pl.y = l8[2] | (l8[3] << 16);
            pl.z = l8[4] | (l8[5] << 16);
            pl.w = l8[6] | (l8[7] << 16);
            const int off = ((row * 256 + c * 16)) ^ ((row & 7) << 4);
            *(uint4*)(Ahi + off) = ph;
            *(uint4*)(Alo + off) = pl;
        }
        __syncthreads();

        // ---- MFMA ----
        f32x4 acc[2][2];
        const f32x4 zero = {0.f, 0.f, 0.f, 0.f};
        acc[0][0] = zero; acc[0][1] = zero; acc[1][0] = zero; acc[1][1] = zero;

        #pragma unroll
        for (int ks = 0; ks < 4; ++ks) {
            const int kbyte = ks * 64 + g * 16;
            bf16x8 ah[2], al[2], bh[2], bl[2];
            #pragma unroll
            for (int m = 0; m < 2; ++m) {
                const int row = wm * 32 + m * 16 + q;
                const int off = (row * 256 + kbyte) ^ ((row & 7) << 4);
                ah[m] = *(const bf16x8*)(Ahi + off);
                al[m] = *(const bf16x8*)(Alo + off);
            }
            #pragma unroll
            for (int n = 0; n < 2; ++n) {
                const int colv = wn * 32 + n * 16 + q;
                const int off = (colv * 256 + kbyte) ^ ((colv & 7) << 4);
                bh[n] = *(const bf16x8*)(Whi + off);
                bl[n] = *(const bf16x8*)(Wlo + off);
            }
            #pragma unroll
            for (int m = 0; m < 2; ++m)
                #pragma unroll
                for (int n = 0; n < 2; ++n)
                    acc[m][n] = __builtin_amdgcn_mfma_f32_16x16x32_bf16(ah[m], bh[n], acc[m][n], 0, 0, 0);
            #pragma unroll
            for (int m = 0; m < 2; ++m)
                #pragma unroll
                for (int n = 0; n < 2; ++n)
                    acc[m][n] = __builtin_amdgcn_mfma_f32_16x16x32_bf16(ah[m], bl[n], acc[m][n], 0, 0, 0);
            #pragma unroll
            for (int m = 0; m < 2; ++m)
                #pragma unroll
                for (int n = 0; n < 2; ++n)
                    acc[m][n] = __builtin_amdgcn_mfma_f32_16x16x32_bf16(al[m], bh[n], acc[m][n], 0, 0, 0);
        }

        // ---- epilogue: bias/relu + store ----
        #pragma unroll
        for (int n = 0; n < 2; ++n) {
            const int colv = wn * 32 + n * 16 + q;
            const float bv = bs[colv];
            #pragma unroll
            for (int m = 0; m < 2; ++m) {
                #pragma unroll
                for (int r = 0; r < 4; ++r) {
                    const int row = e0 + wm * 32 + m * 16 + g * 4 + r;
                    if (row < nTotal) {
                        float v = acc[m][n][r] + bv;
                        if (do_relu) v = fmaxf(v, 0.f);
                        out0[(size_t)row * DD + colv] = v;
                        if (out1) out1[(size_t)row * DD + colv] = v;
                    }
                }
            }
        }
    }
}

// ---------------------------------------------------------------------------
// bond projection + layer-0 aggregation over SORTED edges
// ---------------------------------------------------------------------------
__global__ __launch_bounds__(256)
void bond_proj_agg_kernel(const float* __restrict__ edge_attr,
                          const float* __restrict__ Wb, const float* __restrict__ bb,
                          const int* __restrict__ si, const int* __restrict__ perm,
                          float* __restrict__ h_head0,
                          float* __restrict__ sum_agg, int* __restrict__ max_agg,
                          int E, int N)
{
    __shared__ float Ws[16 * DD];
    __shared__ float bs2[DD];
    __shared__ __align__(16) float ea_s[32][16];
    __shared__ int ii2[32], pm2[32];

    for (int idx = (int)threadIdx.x; idx < 16 * DD; idx += 256) Ws[idx] = Wb[idx];
    if (threadIdx.x < DD) bs2[threadIdx.x] = bb[threadIdx.x];

    const int p0 = blockIdx.x * 32;
    {
        const int t = (int)threadIdx.x;
        const int row = t >> 3;
        const int k2 = (t & 7) * 2;
        const int ppc = min(p0 + row, E - 1);
        const int orig = perm[ppc];
        const float2 v2 = *(const float2*)(edge_attr + (size_t)orig * 16 + k2);
        ea_s[row][k2] = v2.x;
        ea_s[row][k2 + 1] = v2.y;
        if (t < 32) {
            const int q = min(p0 + t, E - 1);
            ii2[t] = si[q];
            pm2[t] = perm[q];
        }
    }
    __syncthreads();

    const int o    = threadIdx.x & 127;
    const int half = threadIdx.x >> 7;

    float wcol[16];
    #pragma unroll
    for (int k = 0; k < 16; ++k) wcol[k] = Ws[k * DD + o];
    const float bo = bs2[o];

    int curNode = ii2[half * 16];
    float rs = 0.f, rm = 0.f;
    #pragma unroll 4
    for (int j = 0; j < 16; ++j) {
        const int row = half * 16 + j;
        const float4* ear = (const float4*)(&ea_s[row][0]);
        const float4 q0 = ear[0], q1 = ear[1], q2 = ear[2], q3 = ear[3];
        float acc = bo;
        acc = fmaf(q0.x, wcol[ 0], acc);
        acc = fmaf(q0.y, wcol[ 1], acc);
        acc = fmaf(q0.z, wcol[ 2], acc);
        acc = fmaf(q0.w, wcol[ 3], acc);
        acc = fmaf(q1.x, wcol[ 4], acc);
        acc = fmaf(q1.y, wcol[ 5], acc);
        acc = fmaf(q1.z, wcol[ 6], acc);
        acc = fmaf(q1.w, wcol[ 7], acc);
        acc = fmaf(q2.x, wcol[ 8], acc);
        acc = fmaf(q2.y, wcol[ 9], acc);
        acc = fmaf(q2.z, wcol[10], acc);
        acc = fmaf(q2.w, wcol[11], acc);
        acc = fmaf(q3.x, wcol[12], acc);
        acc = fmaf(q3.y, wcol[13], acc);
        acc = fmaf(q3.z, wcol[14], acc);
        acc = fmaf(q3.w, wcol[15], acc);
        float v = fmaxf(acc, 0.f);
        const int pe = p0 + row;
        if (pe < E) {
            const int orig = pm2[row];
            if (orig < N) h_head0[(size_t)orig * DD + o] = v;
        } else {
            v = 0.f;
        }
        const int gi = ii2[row];
        if (gi != curNode) {
            atomicAdd(&sum_agg[(size_t)curNode * DD + o], rs);
            atomicMax(&max_agg[(size_t)curNode * DD + o], __float_as_int(rm));
            curNode = gi; rs = v; rm = v;
        } else {
            rs += v; rm = fmaxf(rm, v);
        }
    }
    atomicAdd(&sum_agg[(size_t)curNode * DD + o], rs);
    atomicMax(&max_agg[(size_t)curNode * DD + o], __float_as_int(rm));
}

// ---------------------------------------------------------------------------
// node update (+ fused re-zero of sum/max for the next layer's atomics)
// ---------------------------------------------------------------------------
__global__ __launch_bounds__(256)
void node_update_kernel(float* __restrict__ h_atom, float* __restrict__ sum_agg,
                        int* __restrict__ max_agg, int total4)
{
    const int i = blockIdx.x * 256 + threadIdx.x;
    if (i < total4) {
        float4 h = ((const float4*)h_atom)[i];
        const float4 s = ((const float4*)sum_agg)[i];
        const int4  m = ((const int4*)max_agg)[i];
        h.x *= s.x * __int_as_float(m.x);
        h.y *= s.y * __int_as_float(m.y);
        h.z *= s.z * __int_as_float(m.z);
        h.w *= s.w * __int_as_float(m.w);
        ((float4*)h_atom)[i] = h;
        ((float4*)sum_agg)[i] = make_float4(0.f, 0.f, 0.f, 0.f);
        ((int4*)max_agg)[i]   = make_int4(0, 0, 0, 0);
    }
}

// ---------------------------------------------------------------------------
// edge pass (linearized): v = relu(P[si[p]] - Q[sj[p]] + b)
//   P = PQ rows [0,N), Q = PQ rows [N,2N)
//   run-length sum/max atomics over sorted edges; head store by perm
// one wave per contiguous chunk of sorted edges; lane owns 2 columns (float2)
// ---------------------------------------------------------------------------
__global__ __launch_bounds__(256)
void edge_pass_kernel(const float* __restrict__ PQ, const float* __restrict__ bias,
                      const int* __restrict__ si, const int* __restrict__ sj,
                      const int* __restrict__ perm,
                      float* __restrict__ head_next, int store_head,
                      float* __restrict__ sum_agg, int* __restrict__ max_agg,
                      int E, int N)
{
    const int wid = blockIdx.x * 4 + ((int)threadIdx.x >> 6);
    const int nw  = gridDim.x * 4;
    const int chunk = (E + nw - 1) / nw;
    const int p0 = wid * chunk;
    const int p1 = min(p0 + chunk, E);
    if (p0 >= E) return;

    const int lane = (int)threadIdx.x & 63;
    const int c = lane * 2;
    const float2 bc = *(const float2*)(bias + c);

    int curNode = si[p0];
    float2 Pi = *(const float2*)(PQ + (size_t)curNode * DD + c);
    float2 rs = make_float2(0.f, 0.f), rm = make_float2(0.f, 0.f);

    // depth-1 prefetch of the Q row
    int jn = sj[p0];
    float2 qn = *(const float2*)(PQ + (size_t)(N + jn) * DD + c);

    for (int p = p0; p < p1; ++p) {
        const float2 q = qn;
        const int i = si[p];
        if (p + 1 < p1) {
            const int j2 = sj[p + 1];
            qn = *(const float2*)(PQ + (size_t)(N + j2) * DD + c);
        }
        if (i != curNode) {
            atomicAdd(&sum_agg[(size_t)curNode * DD + c],     rs.x);
            atomicAdd(&sum_agg[(size_t)curNode * DD + c + 1], rs.y);
            atomicMax(&max_agg[(size_t)curNode * DD + c],     __float_as_int(rm.x));
            atomicMax(&max_agg[(size_t)curNode * DD + c + 1], __float_as_int(rm.y));
            curNode = i;
            Pi = *(const float2*)(PQ + (size_t)i * DD + c);
            rs = make_float2(0.f, 0.f);
            rm = make_float2(0.f, 0.f);
        }
        float2 v;
        v.x = fmaxf(Pi.x - q.x + bc.x, 0.f);
        v.y = fmaxf(Pi.y - q.y + bc.y, 0.f);
        rs.x += v.x; rs.y += v.y;
        rm.x = fmaxf(rm.x, v.x); rm.y = fmaxf(rm.y, v.y);
        if (store_head) {
            const int orig = perm[p];
            if (orig < N) *(float2*)(head_next + (size_t)orig * DD + c) = v;
        }
    }
    atomicAdd(&sum_agg[(size_t)curNode * DD + c],     rs.x);
    atomicAdd(&sum_agg[(size_t)curNode * DD + c + 1], rs.y);
    atomicMax(&max_agg[(size_t)curNode * DD + c],     __float_as_int(rm.x));
    atomicMax(&max_agg[(size_t)curNode * DD + c + 1], __float_as_int(rm.y));
}

// ---------------------------------------------------------------------------
// final: msg = sum*max; ha = h_atom * (h_atom * msg);
//        out = [ha, x_proj] @ W_lin + b_lin
// ---------------------------------------------------------------------------
__global__ __launch_bounds__(256)
void final_linear_kernel(const float* __restrict__ h_atom, const float* __restrict__ sum_agg,
                         const int* __restrict__ max_agg, const float* __restrict__ x_proj,
                         const float* __restrict__ Wl, const float* __restrict__ bl,
                         float* __restrict__ out, int Nn)
{
    __shared__ float Wls[256 * 64];
    __shared__ float cat_s[4][256];
    for (int idx = (int)threadIdx.x; idx < 256 * 64; idx += 256) Wls[idx] = Wl[idx];

    const int o  = threadIdx.x & 63;
    const int nl = threadIdx.x >> 6;

    for (int n0 = blockIdx.x * 4; n0 < Nn; n0 += gridDim.x * 4) {
        __syncthreads();
        for (int idx = (int)threadIdx.x; idx < 4 * 256; idx += 256) {
            const int node = n0 + (idx >> 8);
            const int k = idx & 255;
            float v = 0.f;
            if (node < Nn) {
                if (k < 128) {
                    const size_t off = (size_t)node * DD + k;
                    const float ha = h_atom[off];
                    const float m = sum_agg[off] * __int_as_float(max_agg[off]);
                    v = ha * (ha * m);
                } else {
                    v = x_proj[(size_t)node * DD + (k - 128)];
                }
            }
            cat_s[idx >> 8][k] = v;
        }
        __syncthreads();

        const int node = n0 + nl;
        float acc = bl[o];
        #pragma unroll 8
        for (int k = 0; k < 256; ++k) acc = fmaf(cat_s[nl][k], Wls[k * 64 + o], acc);
        if (node < Nn) out[(size_t)node * 64 + o] = acc;
    }
}

// ---------------------------------------------------------------------------
extern "C" void kernel_launch(void* const* d_in, const int* in_sizes, int n_in,
                              void* d_out, int out_size, void* d_ws, size_t ws_size,
                              hipStream_t stream)
{
    const float* x         = (const float*)d_in[0];
    const int*   edge_idx  = (const int*)d_in[1];
    const float* edge_attr = (const float*)d_in[2];
    const float* W_atom    = (const float*)d_in[3];
    const float* b_atom    = (const float*)d_in[4];
    const float* W_bond    = (const float*)d_in[5];
    const float* b_bond    = (const float*)d_in[6];
    const float* W_seq     = (const float*)d_in[7];
    const float* b_seq     = (const float*)d_in[8];
    const float* W_lin     = (const float*)d_in[9];
    const float* b_lin     = (const float*)d_in[10];
    float* out = (float*)d_out;

    const int N = in_sizes[0] / DD;   // 30000
    const int E = in_sizes[1] / 2;    // 480000
    const int* idx_i = edge_idx;
    const int* idx_j = edge_idx + E;

    const size_t nd = (size_t)N * DD;
    float* ws      = (float*)d_ws;
    float* x_proj  = ws;
    float* h_atom  = x_proj + nd;
    float* head    = h_atom + nd;       // single head buffer (edge pass reads only PQ)
    float* sum_agg = head + nd;
    int*   max_agg = (int*)(sum_agg + nd);
    float* PQ      = (float*)(max_agg + nd);   // 2N x 128
    int*   cnt     = (int*)(PQ + 2 * nd);
    int*   cursor  = cnt + N;
    int*   bsum    = cursor + N;
    int*   perm    = bsum + 256;
    int*   si      = perm + E;
    int*   sj      = si + E;

    // ---- counting sort of edges by idx_i ----
    hipMemsetAsync(cnt, 0, (size_t)N * 4, stream);
    hist_kernel<<<(E + 255) / 256, 256, 0, stream>>>(idx_i, cnt, E);
    const int nb_scan = (N + SCB - 1) / SCB;
    scan1_kernel<<<nb_scan, SCB, 0, stream>>>(cnt, cursor, bsum, N);
    scan2_kernel<<<1, SCB, 0, stream>>>(bsum, nb_scan);
    scan3_kernel<<<nb_scan, SCB, 0, stream>>>(cursor, bsum, N);
    scatter_kernel<<<(E + 255) / 256, 256, 0, stream>>>(idx_i, idx_j, cursor, perm, si, sj, E);

    hipMemsetAsync(sum_agg, 0, nd * 4, stream);
    hipMemsetAsync(max_agg, 0, nd * 4, stream);

    // node projection via MFMA: x_proj = h_atom = relu(x @ W_atom + b_atom)
    const int ntiles_n = (N + 127) / 128;
    gemm128_mfma_kernel<<<min(ntiles_n, 256), 1024, 0, stream>>>(
        x, x, N, N, W_atom, b_atom, 1, x_proj, h_atom, ntiles_n);

    bond_proj_agg_kernel<<<(E + 31) / 32, 256, 0, stream>>>(edge_attr, W_bond, b_bond,
                                                            si, perm, head,
                                                            sum_agg, max_agg, E, N);

    const int ntiles_pq = (2 * N + 127) / 128;
    const int upd_blocks = (int)((nd / 4 + 255) / 256);
    for (int l = 0; l < 3; ++l) {
        // h_atom *= msg; re-zero aggs
        node_update_kernel<<<upd_blocks, 256, 0, stream>>>(h_atom, sum_agg, max_agg, (int)(nd / 4));
        // PQ = [h_atom; head] @ W_seq[l]   (no bias/relu)
        gemm128_mfma_kernel<<<256, 1024, 0, stream>>>(
            h_atom, head, N, 2 * N, W_seq + (size_t)l * DD * DD, nullptr, 0,
            PQ, nullptr, ntiles_pq);
        // per-edge: v = relu(P[i] - Q[j] + b); aggregate; store head in place
        edge_pass_kernel<<<2048, 256, 0, stream>>>(
            PQ, b_seq + (size_t)l * DD, si, sj, perm,
            head, (l < 2) ? 1 : 0, sum_agg, max_agg, E, N);
    }

    final_linear_kernel<<<512, 256, 0, stream>>>(h_atom, sum_agg, max_agg, x_proj,
                                                 W_lin, b_lin, out, N);
}

// Round 5
// 503.887 us; speedup vs baseline: 9.7605x; 1.1211x over previous
//
#include <hip/hip_runtime.h>
#include <hip/hip_bf16.h>

#define DD 128   // hidden dim
#define SCB 256  // scan block size
#define CE  256  // edges per block in edge_pass

typedef __attribute__((ext_vector_type(8))) short bf16x8;
typedef __attribute__((ext_vector_type(4))) float f32x4;

__device__ __forceinline__ unsigned bf16_rne(float f) {
    unsigned u = __float_as_uint(f);
    return (u + 0x7fffu + ((u >> 16) & 1u)) >> 16;
}

// ---------------------------------------------------------------------------
// counting-sort preprocessing (sort edges by idx_i)
// ---------------------------------------------------------------------------
__global__ __launch_bounds__(256)
void hist_kernel(const int* __restrict__ idx_i, int* __restrict__ cnt, int E)
{
    const int e = blockIdx.x * 256 + threadIdx.x;
    if (e < E) atomicAdd(&cnt[idx_i[e]], 1);
}

__global__ __launch_bounds__(SCB)
void scan1_kernel(const int* __restrict__ cnt, int* __restrict__ exc,
                  int* __restrict__ bsum, int n)
{
    __shared__ int s[SCB];
    const int i = blockIdx.x * SCB + (int)threadIdx.x;
    const int v = (i < n) ? cnt[i] : 0;
    s[threadIdx.x] = v;
    __syncthreads();
    #pragma unroll
    for (int off = 1; off < SCB; off <<= 1) {
        int t = (threadIdx.x >= off) ? s[threadIdx.x - off] : 0;
        __syncthreads();
        s[threadIdx.x] += t;
        __syncthreads();
    }
    if (i < n) exc[i] = s[threadIdx.x] - v;
    if (threadIdx.x == SCB - 1) bsum[blockIdx.x] = s[threadIdx.x];
}

__global__ __launch_bounds__(SCB)
void scan2_kernel(int* __restrict__ bsum, int nb)
{
    __shared__ int s[SCB];
    const int v = (threadIdx.x < nb) ? bsum[threadIdx.x] : 0;
    s[threadIdx.x] = v;
    __syncthreads();
    #pragma unroll
    for (int off = 1; off < SCB; off <<= 1) {
        int t = (threadIdx.x >= off) ? s[threadIdx.x - off] : 0;
        __syncthreads();
        s[threadIdx.x] += t;
        __syncthreads();
    }
    if (threadIdx.x < nb) bsum[threadIdx.x] = s[threadIdx.x] - v;
}

__global__ __launch_bounds__(SCB)
void scan3_kernel(int* __restrict__ exc, const int* __restrict__ bsum, int n)
{
    const int i = blockIdx.x * SCB + (int)threadIdx.x;
    if (i < n) exc[i] += bsum[i >> 8];
}

__global__ __launch_bounds__(256)
void scatter_kernel(const int* __restrict__ idx_i, const int* __restrict__ idx_j,
                    int* __restrict__ cursor, int* __restrict__ perm,
                    int* __restrict__ si, int* __restrict__ sj, int E)
{
    const int e = blockIdx.x * 256 + threadIdx.x;
    if (e < E) {
        const int n = idx_i[e];
        const int p = atomicAdd(&cursor[n], 1);
        perm[p] = e;
        si[p] = n;
        sj[p] = idx_j[e];
    }
}

// ---------------------------------------------------------------------------
// generic 128-K split-bf16 MFMA GEMM with optional fused node-update:
//   rows r < nA read from A0 (optionally h = h*sum*max, written back, aggs
//   zeroed), else from A1 (row r-nA).
//   out = (relu?)(A @ W) + bias for rows < bias_limit  -> out0 [, out1]
// 1024 threads = 16 waves (4x4), 128x128 tile, C = Ahi*Whi + Ahi*Wlo + Alo*Whi
// ---------------------------------------------------------------------------
__global__ __launch_bounds__(1024)
void gemm128_mfma_kernel(float* __restrict__ A0, const float* __restrict__ A1,
                         int nA, int nTotal,
                         const float* __restrict__ W, const float* __restrict__ bias,
                         int bias_limit, int do_relu, int update,
                         float* __restrict__ sum_agg, int* __restrict__ max_agg,
                         float* __restrict__ out0, float* __restrict__ out1,
                         int ntiles)
{
    // LDS: Whi 32K | Wlo 32K | Ahi 32K | Alo 32K | bias 512
    __shared__ __align__(16) unsigned char SM[131584];
    char*  const Whi = (char*)SM;
    char*  const Wlo = (char*)SM + 32768;
    char*  const Ahi = (char*)SM + 65536;
    char*  const Alo = (char*)SM + 98304;
    float* const Wf  = (float*)(SM + 65536);
    float* const bs  = (float*)(SM + 131072);

    const int t = (int)threadIdx.x;

    // ---- prologue phase 1: coalesced W f32 -> LDS scratch ----
    {
        const float4* Wg = (const float4*)W;
        float4* Wd = (float4*)Wf;
        #pragma unroll
        for (int i = 0; i < 4; ++i) Wd[t + i * 1024] = Wg[t + i * 1024];
        if (t < DD) bs[t] = bias ? bias[t] : 0.f;
    }
    __syncthreads();
    // ---- prologue phase 2: split + transpose into Whi/Wlo ----
    {
        const int col = t >> 3;
        const int kb  = (t & 7) * 16;
        unsigned h16[16], l16[16];
        #pragma unroll
        for (int j = 0; j < 16; ++j) {
            const float w = Wf[(size_t)(kb + j) * DD + col];
            const unsigned hb = bf16_rne(w);
            const float hf = __uint_as_float(hb << 16);
            h16[j] = hb;
            l16[j] = bf16_rne(w - hf);
        }
        #pragma unroll
        for (int c = 0; c < 2; ++c) {
            uint4 ph, pl;
            ph.x = h16[c*8+0] | (h16[c*8+1] << 16);
            ph.y = h16[c*8+2] | (h16[c*8+3] << 16);
            ph.z = h16[c*8+4] | (h16[c*8+5] << 16);
            ph.w = h16[c*8+6] | (h16[c*8+7] << 16);
            pl.x = l16[c*8+0] | (l16[c*8+1] << 16);
            pl.y = l16[c*8+2] | (l16[c*8+3] << 16);
            pl.z = l16[c*8+4] | (l16[c*8+5] << 16);
            pl.w = l16[c*8+6] | (l16[c*8+7] << 16);
            const int off = ((col * 256 + (kb + c * 8) * 2)) ^ ((col & 7) << 4);
            *(uint4*)(Whi + off) = ph;
            *(uint4*)(Wlo + off) = pl;
        }
    }

    const int w  = t >> 6;
    const int l  = t & 63;
    const int wm = w >> 2;
    const int wn = w & 3;
    const int g  = l >> 4;
    const int q  = l & 15;

    for (int tile = blockIdx.x; tile < ntiles; tile += gridDim.x) {
        const int e0 = tile * 128;
        __syncthreads();

        // ---- stage A tile (+ optional fused node-update), swizzled write ----
        #pragma unroll
        for (int i = 0; i < 2; ++i) {
            const int task = t + i * 1024;
            const int row  = task >> 4;
            const int c    = task & 15;
            const int rr = min(e0 + row, nTotal - 1);
            float d[8];
            if (rr < nA) {
                float* ph0 = A0 + (size_t)rr * DD + c * 8;
                const float4 a0 = *(const float4*)ph0;
                const float4 a1 = *(const float4*)(ph0 + 4);
                if (update) {
                    float* sp = sum_agg + (size_t)rr * DD + c * 8;
                    int*   mp = max_agg + (size_t)rr * DD + c * 8;
                    const float4 s0 = *(const float4*)sp;
                    const float4 s1 = *(const float4*)(sp + 4);
                    const int4   m0 = *(const int4*)mp;
                    const int4   m1 = *(const int4*)(mp + 4);
                    d[0] = a0.x * s0.x * __int_as_float(m0.x);
                    d[1] = a0.y * s0.y * __int_as_float(m0.y);
                    d[2] = a0.z * s0.z * __int_as_float(m0.z);
                    d[3] = a0.w * s0.w * __int_as_float(m0.w);
                    d[4] = a1.x * s1.x * __int_as_float(m1.x);
                    d[5] = a1.y * s1.y * __int_as_float(m1.y);
                    d[6] = a1.z * s1.z * __int_as_float(m1.z);
                    d[7] = a1.w * s1.w * __int_as_float(m1.w);
                    // write back updated h_atom; zero aggs for next layer
                    *(float4*)ph0       = make_float4(d[0], d[1], d[2], d[3]);
                    *(float4*)(ph0 + 4) = make_float4(d[4], d[5], d[6], d[7]);
                    *(float4*)sp       = make_float4(0.f, 0.f, 0.f, 0.f);
                    *(float4*)(sp + 4) = make_float4(0.f, 0.f, 0.f, 0.f);
                    *(int4*)mp       = make_int4(0, 0, 0, 0);
                    *(int4*)(mp + 4) = make_int4(0, 0, 0, 0);
                } else {
                    d[0] = a0.x; d[1] = a0.y; d[2] = a0.z; d[3] = a0.w;
                    d[4] = a1.x; d[5] = a1.y; d[6] = a1.z; d[7] = a1.w;
                }
            } else {
                const float* pa = A1 + (size_t)(rr - nA) * DD + c * 8;
                const float4 a0 = *(const float4*)pa;
                const float4 a1 = *(const float4*)(pa + 4);
                d[0] = a0.x; d[1] = a0.y; d[2] = a0.z; d[3] = a0.w;
                d[4] = a1.x; d[5] = a1.y; d[6] = a1.z; d[7] = a1.w;
            }
            unsigned h8[8], l8[8];
            #pragma unroll
            for (int j = 0; j < 8; ++j) {
                const unsigned hb = bf16_rne(d[j]);
                const float hf = __uint_as_float(hb << 16);
                h8[j] = hb;
                l8[j] = bf16_rne(d[j] - hf);
            }
            uint4 ph, pl;
            ph.x = h8[0] | (h8[1] << 16);
            ph.y = h8[2] | (h8[3] << 16);
            ph.z = h8[4] | (h8[5] << 16);
            ph.w = h8[6] | (h8[7] << 16);
            pl.x = l8[0] | (l8[1] << 16);
            pl.y = l8[2] | (l8[3] << 16);
            pl.z = l8[4] | (l8[5] << 16);
            pl.w = l8[6] | (l8[7] << 16);
            const int off = ((row * 256 + c * 16)) ^ ((row & 7) << 4);
            *(uint4*)(Ahi + off) = ph;
            *(uint4*)(Alo + off) = pl;
        }
        __syncthreads();

        // ---- MFMA ----
        f32x4 acc[2][2];
        const f32x4 zero = {0.f, 0.f, 0.f, 0.f};
        acc[0][0] = zero; acc[0][1] = zero; acc[1][0] = zero; acc[1][1] = zero;

        #pragma unroll
        for (int ks = 0; ks < 4; ++ks) {
            const int kbyte = ks * 64 + g * 16;
            bf16x8 ah[2], al[2], bh[2], bl[2];
            #pragma unroll
            for (int m = 0; m < 2; ++m) {
                const int row = wm * 32 + m * 16 + q;
                const int off = (row * 256 + kbyte) ^ ((row & 7) << 4);
                ah[m] = *(const bf16x8*)(Ahi + off);
                al[m] = *(const bf16x8*)(Alo + off);
            }
            #pragma unroll
            for (int n = 0; n < 2; ++n) {
                const int colv = wn * 32 + n * 16 + q;
                const int off = (colv * 256 + kbyte) ^ ((colv & 7) << 4);
                bh[n] = *(const bf16x8*)(Whi + off);
                bl[n] = *(const bf16x8*)(Wlo + off);
            }
            #pragma unroll
            for (int m = 0; m < 2; ++m)
                #pragma unroll
                for (int n = 0; n < 2; ++n)
                    acc[m][n] = __builtin_amdgcn_mfma_f32_16x16x32_bf16(ah[m], bh[n], acc[m][n], 0, 0, 0);
            #pragma unroll
            for (int m = 0; m < 2; ++m)
                #pragma unroll
                for (int n = 0; n < 2; ++n)
                    acc[m][n] = __builtin_amdgcn_mfma_f32_16x16x32_bf16(ah[m], bl[n], acc[m][n], 0, 0, 0);
            #pragma unroll
            for (int m = 0; m < 2; ++m)
                #pragma unroll
                for (int n = 0; n < 2; ++n)
                    acc[m][n] = __builtin_amdgcn_mfma_f32_16x16x32_bf16(al[m], bh[n], acc[m][n], 0, 0, 0);
        }

        // ---- epilogue: bias (rows < bias_limit) / relu + store ----
        #pragma unroll
        for (int n = 0; n < 2; ++n) {
            const int colv = wn * 32 + n * 16 + q;
            const float bv = bs[colv];
            #pragma unroll
            for (int m = 0; m < 2; ++m) {
                #pragma unroll
                for (int r = 0; r < 4; ++r) {
                    const int row = e0 + wm * 32 + m * 16 + g * 4 + r;
                    if (row < nTotal) {
                        float v = acc[m][n][r] + ((row < bias_limit) ? bv : 0.f);
                        if (do_relu) v = fmaxf(v, 0.f);
                        out0[(size_t)row * DD + colv] = v;
                        if (out1) out1[(size_t)row * DD + colv] = v;
                    }
                }
            }
        }
    }
}

// ---------------------------------------------------------------------------
// bond projection + layer-0 aggregation over SORTED edges
// ---------------------------------------------------------------------------
__global__ __launch_bounds__(256)
void bond_proj_agg_kernel(const float* __restrict__ edge_attr,
                          const float* __restrict__ Wb, const float* __restrict__ bb,
                          const int* __restrict__ si, const int* __restrict__ perm,
                          float* __restrict__ h_head0,
                          float* __restrict__ sum_agg, int* __restrict__ max_agg,
                          int E, int N)
{
    __shared__ float Ws[16 * DD];
    __shared__ float bs2[DD];
    __shared__ __align__(16) float ea_s[32][16];
    __shared__ int ii2[32], pm2[32];

    for (int idx = (int)threadIdx.x; idx < 16 * DD; idx += 256) Ws[idx] = Wb[idx];
    if (threadIdx.x < DD) bs2[threadIdx.x] = bb[threadIdx.x];

    const int p0 = blockIdx.x * 32;
    {
        const int t = (int)threadIdx.x;
        const int row = t >> 3;
        const int k2 = (t & 7) * 2;
        const int ppc = min(p0 + row, E - 1);
        const int orig = perm[ppc];
        const float2 v2 = *(const float2*)(edge_attr + (size_t)orig * 16 + k2);
        ea_s[row][k2] = v2.x;
        ea_s[row][k2 + 1] = v2.y;
        if (t < 32) {
            const int q = min(p0 + t, E - 1);
            ii2[t] = si[q];
            pm2[t] = perm[q];
        }
    }
    __syncthreads();

    const int o    = threadIdx.x & 127;
    const int half = threadIdx.x >> 7;

    float wcol[16];
    #pragma unroll
    for (int k = 0; k < 16; ++k) wcol[k] = Ws[k * DD + o];
    const float bo = bs2[o];

    int curNode = ii2[half * 16];
    float rs = 0.f, rm = 0.f;
    #pragma unroll 4
    for (int j = 0; j < 16; ++j) {
        const int row = half * 16 + j;
        const float4* ear = (const float4*)(&ea_s[row][0]);
        const float4 q0 = ear[0], q1 = ear[1], q2 = ear[2], q3 = ear[3];
        float acc = bo;
        acc = fmaf(q0.x, wcol[ 0], acc);
        acc = fmaf(q0.y, wcol[ 1], acc);
        acc = fmaf(q0.z, wcol[ 2], acc);
        acc = fmaf(q0.w, wcol[ 3], acc);
        acc = fmaf(q1.x, wcol[ 4], acc);
        acc = fmaf(q1.y, wcol[ 5], acc);
        acc = fmaf(q1.z, wcol[ 6], acc);
        acc = fmaf(q1.w, wcol[ 7], acc);
        acc = fmaf(q2.x, wcol[ 8], acc);
        acc = fmaf(q2.y, wcol[ 9], acc);
        acc = fmaf(q2.z, wcol[10], acc);
        acc = fmaf(q2.w, wcol[11], acc);
        acc = fmaf(q3.x, wcol[12], acc);
        acc = fmaf(q3.y, wcol[13], acc);
        acc = fmaf(q3.z, wcol[14], acc);
        acc = fmaf(q3.w, wcol[15], acc);
        float v = fmaxf(acc, 0.f);
        const int pe = p0 + row;
        if (pe < E) {
            const int orig = pm2[row];
            if (orig < N) h_head0[(size_t)orig * DD + o] = v;
        } else {
            v = 0.f;
        }
        const int gi = ii2[row];
        if (gi != curNode) {
            atomicAdd(&sum_agg[(size_t)curNode * DD + o], rs);
            atomicMax(&max_agg[(size_t)curNode * DD + o], __float_as_int(rm));
            curNode = gi; rs = v; rm = v;
        } else {
            rs += v; rm = fmaxf(rm, v);
        }
    }
    atomicAdd(&sum_agg[(size_t)curNode * DD + o], rs);
    atomicMax(&max_agg[(size_t)curNode * DD + o], __float_as_int(rm));
}

// ---------------------------------------------------------------------------
// edge pass (linearized): v = relu(P[si[p]] - Q[sj[p]])   (bias folded into P)
//   P = PQ rows [0,N), Q = PQ rows [N,2N)
//   block stages si/sj/perm for CE edges into LDS; 4 waves x 64 edges each,
//   4-deep statically-indexed Q-row prefetch; run-length sum/max atomics.
// ---------------------------------------------------------------------------
__global__ __launch_bounds__(256)
void edge_pass_kernel(const float* __restrict__ PQ,
                      const int* __restrict__ si, const int* __restrict__ sj,
                      const int* __restrict__ perm,
                      float* __restrict__ head_next, int store_head,
                      float* __restrict__ sum_agg, int* __restrict__ max_agg,
                      int E, int N)
{
    __shared__ int si_s[CE], sj_s[CE], pm_s[CE];
    const int p0b = blockIdx.x * CE;
    if (p0b >= E) return;
    const int t = (int)threadIdx.x;
    {
        const int p = min(p0b + t, E - 1);
        si_s[t] = si[p];
        sj_s[t] = sj[p];
        pm_s[t] = perm[p];
    }
    __syncthreads();

    const int w    = t >> 6;         // wave 0..3
    const int lane = t & 63;
    const int c    = lane * 2;
    const int q0   = w * 64;         // wave's first local edge
    const int pg0  = p0b + q0;       // global first edge of this wave
    if (pg0 >= E) return;

    const float* __restrict__ Qbase = PQ + (size_t)N * DD + c;

    // 4-deep prefetch pipeline, statically indexed (manual rotation)
    float2 qa = *(const float2*)(Qbase + (size_t)sj_s[q0 + 0] * DD);
    float2 qb = *(const float2*)(Qbase + (size_t)sj_s[q0 + 1] * DD);
    float2 qc = *(const float2*)(Qbase + (size_t)sj_s[q0 + 2] * DD);
    float2 qd = *(const float2*)(Qbase + (size_t)sj_s[q0 + 3] * DD);

    int curNode = si_s[q0];
    float2 Pi = *(const float2*)(PQ + (size_t)curNode * DD + c);
    float2 rs = make_float2(0.f, 0.f), rm = make_float2(0.f, 0.f);

    #define EP_STEP(K, QREG)                                                     \
    {                                                                            \
        const int kk = (K);                                                      \
        const int i = si_s[q0 + kk];                                             \
        if (i != curNode) {                                                      \
            atomicAdd(&sum_agg[(size_t)curNode * DD + c],     rs.x);             \
            atomicAdd(&sum_agg[(size_t)curNode * DD + c + 1], rs.y);             \
            atomicMax(&max_agg[(size_t)curNode * DD + c],     __float_as_int(rm.x)); \
            atomicMax(&max_agg[(size_t)curNode * DD + c + 1], __float_as_int(rm.y)); \
            curNode = i;                                                         \
            Pi = *(const float2*)(PQ + (size_t)i * DD + c);                      \
            rs = make_float2(0.f, 0.f);                                          \
            rm = make_float2(0.f, 0.f);                                          \
        }                                                                        \
        float2 v;                                                                \
        v.x = fmaxf(Pi.x - QREG.x, 0.f);                                         \
        v.y = fmaxf(Pi.y - QREG.y, 0.f);                                         \
        if (pg0 + kk >= E) { v.x = 0.f; v.y = 0.f; }                             \
        rs.x += v.x; rs.y += v.y;                                                \
        rm.x = fmaxf(rm.x, v.x); rm.y = fmaxf(rm.y, v.y);                        \
        if (store_head && (pg0 + kk) < E) {                                      \
            const int orig = pm_s[q0 + kk];                                      \
            if (orig < N) *(float2*)(head_next + (size_t)orig * DD + c) = v;     \
        }                                                                        \
        if (kk + 4 < 64)                                                         \
            QREG = *(const float2*)(Qbase + (size_t)sj_s[q0 + kk + 4] * DD);     \
    }

    #pragma unroll
    for (int k = 0; k < 64; k += 4) {
        EP_STEP(k + 0, qa);
        EP_STEP(k + 1, qb);
        EP_STEP(k + 2, qc);
        EP_STEP(k + 3, qd);
    }
    #undef EP_STEP

    atomicAdd(&sum_agg[(size_t)curNode * DD + c],     rs.x);
    atomicAdd(&sum_agg[(size_t)curNode * DD + c + 1], rs.y);
    atomicMax(&max_agg[(size_t)curNode * DD + c],     __float_as_int(rm.x));
    atomicMax(&max_agg[(size_t)curNode * DD + c + 1], __float_as_int(rm.y));
}

// ---------------------------------------------------------------------------
// final: msg = sum*max; ha = h_atom * (h_atom * msg);
//        out = [ha, x_proj] @ W_lin + b_lin
// ---------------------------------------------------------------------------
__global__ __launch_bounds__(256)
void final_linear_kernel(const float* __restrict__ h_atom, const float* __restrict__ sum_agg,
                         const int* __restrict__ max_agg, const float* __restrict__ x_proj,
                         const float* __restrict__ Wl, const float* __restrict__ bl,
                         float* __restrict__ out, int Nn)
{
    __shared__ float Wls[256 * 64];
    __shared__ float cat_s[4][256];
    for (int idx = (int)threadIdx.x; idx < 256 * 64; idx += 256) Wls[idx] = Wl[idx];

    const int o  = threadIdx.x & 63;
    const int nl = threadIdx.x >> 6;

    for (int n0 = blockIdx.x * 4; n0 < Nn; n0 += gridDim.x * 4) {
        __syncthreads();
        for (int idx = (int)threadIdx.x; idx < 4 * 256; idx += 256) {
            const int node = n0 + (idx >> 8);
            const int k = idx & 255;
            float v = 0.f;
            if (node < Nn) {
                if (k < 128) {
                    const size_t off = (size_t)node * DD + k;
                    const float ha = h_atom[off];
                    const float m = sum_agg[off] * __int_as_float(max_agg[off]);
                    v = ha * (ha * m);
                } else {
                    v = x_proj[(size_t)node * DD + (k - 128)];
                }
            }
            cat_s[idx >> 8][k] = v;
        }
        __syncthreads();

        const int node = n0 + nl;
        float acc = bl[o];
        #pragma unroll 8
        for (int k = 0; k < 256; ++k) acc = fmaf(cat_s[nl][k], Wls[k * 64 + o], acc);
        if (node < Nn) out[(size_t)node * 64 + o] = acc;
    }
}

// ---------------------------------------------------------------------------
extern "C" void kernel_launch(void* const* d_in, const int* in_sizes, int n_in,
                              void* d_out, int out_size, void* d_ws, size_t ws_size,
                              hipStream_t stream)
{
    const float* x         = (const float*)d_in[0];
    const int*   edge_idx  = (const int*)d_in[1];
    const float* edge_attr = (const float*)d_in[2];
    const float* W_atom    = (const float*)d_in[3];
    const float* b_atom    = (const float*)d_in[4];
    const float* W_bond    = (const float*)d_in[5];
    const float* b_bond    = (const float*)d_in[6];
    const float* W_seq     = (const float*)d_in[7];
    const float* b_seq     = (const float*)d_in[8];
    const float* W_lin     = (const float*)d_in[9];
    const float* b_lin     = (const float*)d_in[10];
    float* out = (float*)d_out;

    const int N = in_sizes[0] / DD;   // 30000
    const int E = in_sizes[1] / 2;    // 480000
    const int* idx_i = edge_idx;
    const int* idx_j = edge_idx + E;

    const size_t nd = (size_t)N * DD;
    float* ws      = (float*)d_ws;
    float* x_proj  = ws;
    float* h_atom  = x_proj + nd;
    float* head    = h_atom + nd;       // single head buffer (edge pass reads only PQ)
    float* sum_agg = head + nd;
    int*   max_agg = (int*)(sum_agg + nd);
    float* PQ      = (float*)(max_agg + nd);   // 2N x 128
    int*   cnt     = (int*)(PQ + 2 * nd);
    int*   cursor  = cnt + N;
    int*   bsum    = cursor + N;
    int*   perm    = bsum + 256;
    int*   si      = perm + E;
    int*   sj      = si + E;

    // ---- counting sort of edges by idx_i ----
    hipMemsetAsync(cnt, 0, (size_t)N * 4, stream);
    hist_kernel<<<(E + 255) / 256, 256, 0, stream>>>(idx_i, cnt, E);
    const int nb_scan = (N + SCB - 1) / SCB;
    scan1_kernel<<<nb_scan, SCB, 0, stream>>>(cnt, cursor, bsum, N);
    scan2_kernel<<<1, SCB, 0, stream>>>(bsum, nb_scan);
    scan3_kernel<<<nb_scan, SCB, 0, stream>>>(cursor, bsum, N);
    scatter_kernel<<<(E + 255) / 256, 256, 0, stream>>>(idx_i, idx_j, cursor, perm, si, sj, E);

    hipMemsetAsync(sum_agg, 0, nd * 4, stream);
    hipMemsetAsync(max_agg, 0, nd * 4, stream);

    // node projection via MFMA: x_proj = h_atom = relu(x @ W_atom + b_atom)
    const int ntiles_n = (N + 127) / 128;
    gemm128_mfma_kernel<<<min(ntiles_n, 256), 1024, 0, stream>>>(
        (float*)x, x, N, N, W_atom, b_atom, N, 1, 0, nullptr, nullptr,
        x_proj, h_atom, ntiles_n);

    bond_proj_agg_kernel<<<(E + 31) / 32, 256, 0, stream>>>(edge_attr, W_bond, b_bond,
                                                            si, perm, head,
                                                            sum_agg, max_agg, E, N);

    const int ntiles_pq = (2 * N + 127) / 128;
    const int ep_blocks = (E + CE - 1) / CE;
    for (int l = 0; l < 3; ++l) {
        // PQ = [(h_atom*=sum*max); head] @ W_seq[l]; P rows get +b_seq[l];
        // h_atom written back, aggs zeroed (fused node-update)
        gemm128_mfma_kernel<<<256, 1024, 0, stream>>>(
            h_atom, head, N, 2 * N, W_seq + (size_t)l * DD * DD,
            b_seq + (size_t)l * DD, N, 0, 1, sum_agg, max_agg,
            PQ, nullptr, ntiles_pq);
        // per-edge: v = relu(P[i] - Q[j]); aggregate; store head in place
        edge_pass_kernel<<<ep_blocks, 256, 0, stream>>>(
            PQ, si, sj, perm, head, (l < 2) ? 1 : 0, sum_agg, max_agg, E, N);
    }

    final_linear_kernel<<<512, 256, 0, stream>>>(h_atom, sum_agg, max_agg, x_proj,
                                                 W_lin, b_lin, out, N);
}